// Round 16
// baseline (255.845 us; speedup 1.0000x reference)
//
#include <hip/hip_runtime.h>
#include <hip/hip_bf16.h>
#include <cstdint>
#include <cstddef>

#define NN 50000
#define NE 500000
#define GD 256
#define H1 128
#define H2 128
#define NREL 8
#define NBASES 30
#define XRLD (NREL * H1)   // 1024
#define NCHUNKS ((NN + 1023) / 1024)  // 49

typedef __attribute__((ext_vector_type(8))) short bf16x8;
typedef __attribute__((ext_vector_type(4))) float f32x4;
typedef __attribute__((ext_vector_type(8))) unsigned short u16x8;

__device__ __forceinline__ float lrelu(float x) { return x > 0.f ? x : 0.2f * x; }

// manual RTNE (no NaN path) — faster than __float2bfloat16, proven R13
__device__ __forceinline__ unsigned short f2bf(float x) {
  union { float f; uint32_t u; } v; v.f = x;
  uint32_t r = v.u + 0x7FFF + ((v.u >> 16) & 1);
  return (unsigned short)(r >> 16);
}
__device__ __forceinline__ float bf2f(unsigned short u) {
  union { uint32_t u; float f; } v; v.u = ((uint32_t)u) << 16;
  return v.f;
}

template <int N>
__device__ __forceinline__ void wait_vmcnt() {
  asm volatile("s_waitcnt vmcnt(%0)" :: "n"(N) : "memory");
}

__device__ __forceinline__ void gload_lds(const unsigned short* gp, unsigned short* lp) {
  __builtin_amdgcn_global_load_lds(
      (const __attribute__((address_space(1))) void*)gp,
      (__attribute__((address_space(3))) void*)lp, 16, 0, 0);
}

// ---- cast nf fp32 -> bf16 ----
__global__ void k_cast(const float* __restrict__ in, unsigned short* __restrict__ out) {
  int i = blockIdx.x * 256 + threadIdx.x;
  const float4* p = (const float4*)(in + (size_t)i * 8);
  float4 a = p[0], b = p[1];
  u16x8 r;
  r[0] = f2bf(a.x); r[1] = f2bf(a.y); r[2] = f2bf(a.z); r[3] = f2bf(a.w);
  r[4] = f2bf(b.x); r[5] = f2bf(b.y); r[6] = f2bf(b.z); r[7] = f2bf(b.w);
  *(u16x8*)(out + (size_t)i * 8) = r;
}

// ---- wrb_t[n][k] bf16 [1024][256] ----
__global__ void k_wr(const float* __restrict__ basis, const float* __restrict__ comp,
                     unsigned short* __restrict__ wrb_t) {
  int idx = blockIdx.x * 256 + threadIdx.x;
  int n = idx >> 8;
  int k = idx & 255;
  int r = n >> 7, o = n & 127;
  float acc = 0.f;
  #pragma unroll
  for (int b = 0; b < NBASES; b++)
    acc += comp[r * NBASES + b] * basis[((size_t)b * GD + k) * H1 + o];
  wrb_t[idx] = f2bf(acc);
}

// ---- prep2: one block per column c. LDS-stage wcat[:,c], parallel dots. ----
__global__ __launch_bounds__(256)
void k_prep2(const float* __restrict__ root, const float* __restrict__ w_l,
             const float* __restrict__ w_r, const float* __restrict__ bias1,
             unsigned short* __restrict__ btf, float* __restrict__ biasv) {
  __shared__ float wcol[128];
  __shared__ float red[128];
  int c = blockIdx.x;        // 0..255
  int t = threadIdx.x;       // 0..255
  if (t < 128) {
    float v = (c < H2) ? w_l[t * H2 + c] : w_r[t * H2 + (c - H2)];
    wcol[t] = v;
    btf[c * 384 + t] = f2bf(v);
  }
  __syncthreads();
  const float4* rp = (const float4*)(root + (size_t)t * H1);
  float acc = 0.f;
  #pragma unroll
  for (int j4 = 0; j4 < 32; j4++) {
    float4 r4 = rp[j4];
    acc += r4.x * wcol[j4 * 4 + 0] + r4.y * wcol[j4 * 4 + 1] +
           r4.z * wcol[j4 * 4 + 2] + r4.w * wcol[j4 * 4 + 3];
  }
  btf[c * 384 + 128 + t] = f2bf(acc);
  if (t < 128) red[t] = bias1[t] * wcol[t];
  __syncthreads();
  for (int st = 64; st > 0; st >>= 1) {
    if (t < st) red[t] += red[t + st];
    __syncthreads();
  }
  if (t == 0) biasv[c] = red[0];
}

// ---- xr GEMM: wave tile 64x64 (WM=4), block 128x128, 3-buf BK=32, counted vmcnt ----
template <int K, int WM>
__global__ __launch_bounds__(256, 3)
void k_mgemm(const unsigned short* __restrict__ A, const unsigned short* __restrict__ Bt,
             unsigned short* __restrict__ C, int M, int N, int gx) {
  constexpr int BM = WM * 32;
  constexpr int ACH = BM * 4;
  constexpr int TCH = ACH + 512;
  constexpr int LPT = TCH / 256;
  constexpr int NS = K / 32;
  constexpr int ABUF = BM * 32;
  constexpr int BBUF = 128 * 32;
  extern __shared__ unsigned short lds[];
  const int tid = threadIdx.x;
  const int lane = tid & 63;
  const int wave = tid >> 6;

  const int nwg = gridDim.x;
  const int q = nwg >> 3, r = nwg & 7;
  const int xcd = blockIdx.x & 7, bi = blockIdx.x >> 3;
  const int wg = (xcd < r ? xcd * (q + 1) : r * (q + 1) + (xcd - r) * q) + bi;
  const int bx = wg % gx;
  const int by = wg / gx;
  const int row0 = by * BM;
  const int colb = bx * 128;
  const int wcol = (wave & 1) * 64;
  const int wrow = (wave >> 1) * (WM * 16);
  const int lr = lane & 15;
  const int lko = lane >> 4;

  f32x4 acc[WM][4];
  #pragma unroll
  for (int i = 0; i < WM; i++)
    #pragma unroll
    for (int j = 0; j < 4; j++) acc[i][j] = (f32x4){0.f, 0.f, 0.f, 0.f};

  auto stage = [&](int k0, int b) {
    unsigned short* as = lds + b * ABUF;
    unsigned short* bs = lds + 3 * ABUF + b * BBUF;
    #pragma unroll
    for (int it = 0; it < LPT; it++) {
      int ci = it * 256 + tid;
      if (ci < ACH) {
        int row = ci >> 2, cs = ci & 3;
        int s = (row & 3) ^ ((row >> 2) & 3);
        int gm = row0 + row; if (gm >= M) gm = M - 1;
        gload_lds(A + (size_t)gm * K + k0 + ((cs ^ s) << 3), as + (size_t)ci * 8);
      } else {
        int cj = ci - ACH;
        int row = cj >> 2, cs = cj & 3;
        int s = (row & 3) ^ ((row >> 2) & 3);
        gload_lds(Bt + (size_t)(colb + row) * K + k0 + ((cs ^ s) << 3), bs + (size_t)cj * 8);
      }
    }
  };

  auto compute = [&](int b) {
    const unsigned short* as = lds + b * ABUF;
    const unsigned short* bs = lds + 3 * ABUF + b * BBUF;
    bf16x8 af[WM], bfr[4];
    #pragma unroll
    for (int mb = 0; mb < WM; mb++) {
      int rowL = wrow + mb * 16 + lr;
      int s = (rowL & 3) ^ ((rowL >> 2) & 3);
      af[mb] = *(const bf16x8*)&as[rowL * 32 + ((lko ^ s) << 3)];
    }
    #pragma unroll
    for (int nb = 0; nb < 4; nb++) {
      int colL = wcol + nb * 16 + lr;
      int s = (colL & 3) ^ ((colL >> 2) & 3);
      bfr[nb] = *(const bf16x8*)&bs[colL * 32 + ((lko ^ s) << 3)];
    }
    #pragma unroll
    for (int mb = 0; mb < WM; mb++)
      #pragma unroll
      for (int nb = 0; nb < 4; nb++)
        acc[mb][nb] = __builtin_amdgcn_mfma_f32_16x16x32_bf16(af[mb], bfr[nb], acc[mb][nb], 0, 0, 0);
  };

  stage(0, 0);
  stage(32, 1);
  wait_vmcnt<LPT>();
  __builtin_amdgcn_sched_barrier(0);
  __builtin_amdgcn_s_barrier();
  #pragma unroll
  for (int s = 0; s < NS; s++) {
    if (s + 2 < NS) stage((s + 2) * 32, (s + 2) % 3);
    compute(s % 3);
    if (s + 1 < NS) {
      if (s + 2 < NS) wait_vmcnt<LPT>();
      else            wait_vmcnt<0>();
      __builtin_amdgcn_sched_barrier(0);
      __builtin_amdgcn_s_barrier();
    }
  }

  __syncthreads();
  unsigned short* Cs = lds;                // [BM][128]
  const int orow = lko * 4;
  #pragma unroll
  for (int mb = 0; mb < WM; mb++) {
    #pragma unroll
    for (int i = 0; i < 4; i++) {
      int row = wrow + mb * 16 + orow + i;
      int sw = (row & 7) << 3;
      #pragma unroll
      for (int nb = 0; nb < 4; nb++) {
        int col = wcol + nb * 16 + lr;
        Cs[row * 128 + (col ^ sw)] = f2bf(acc[mb][nb][i]);
      }
    }
  }
  __syncthreads();
  #pragma unroll
  for (int it = 0; it < BM / 16; it++) {
    int off = it * 256 + tid;
    int row = off >> 4, jb = off & 15;
    int grow = row0 + row;
    if (grow < M) {
      int idx = row * 128 + ((jb * 8) ^ ((row & 7) << 3));
      *(u16x8*)&C[(size_t)grow * N + colb + jb * 8] = *(const u16x8*)&Cs[idx];
    }
  }
}

// ---- fused GEMM: [xl|xrt] = [agg|nf] @ btf^T + biasv; split compact outputs ----
__global__ __launch_bounds__(256, 3)
void k_fused(const unsigned short* __restrict__ A1, const unsigned short* __restrict__ A2,
             const unsigned short* __restrict__ Bt, const float* __restrict__ biasv,
             unsigned short* __restrict__ xl, unsigned short* __restrict__ xrt, int M) {
  constexpr int K = 384, NS = 12, LPT = 4;
  extern __shared__ unsigned short lds[];
  const int tid = threadIdx.x;
  const int lane = tid & 63;
  const int wave = tid >> 6;

  const int nwg = gridDim.x;
  const int q = nwg >> 3, r = nwg & 7;
  const int xcd = blockIdx.x & 7, bi = blockIdx.x >> 3;
  const int wg = (xcd < r ? xcd * (q + 1) : r * (q + 1) + (xcd - r) * q) + bi;
  const int bx = wg & 1;
  const int by = wg >> 1;
  const int row0 = by * 128;
  const int colb = bx * 128;
  const int wcol = (wave & 1) * 64;
  const int wrow = (wave >> 1) * 64;
  const int lr = lane & 15;
  const int lko = lane >> 4;

  f32x4 acc[4][4];
  #pragma unroll
  for (int i = 0; i < 4; i++)
    #pragma unroll
    for (int j = 0; j < 4; j++) acc[i][j] = (f32x4){0.f, 0.f, 0.f, 0.f};

  auto stage = [&](int k0, int b) {
    unsigned short* as = lds + b * 4096;
    unsigned short* bs = lds + 3 * 4096 + b * 4096;
    #pragma unroll
    for (int it = 0; it < LPT; it++) {
      int ci = it * 256 + tid;
      if (ci < 512) {
        int row = ci >> 2, cs = ci & 3;
        int s = (row & 3) ^ ((row >> 2) & 3);
        int gm = row0 + row; if (gm >= M) gm = M - 1;
        const unsigned short* gp;
        if (k0 < 128) gp = A1 + (size_t)gm * 128 + k0 + ((cs ^ s) << 3);
        else          gp = A2 + (size_t)gm * 256 + (k0 - 128) + ((cs ^ s) << 3);
        gload_lds(gp, as + (size_t)ci * 8);
      } else {
        int cj = ci - 512;
        int row = cj >> 2, cs = cj & 3;
        int s = (row & 3) ^ ((row >> 2) & 3);
        gload_lds(Bt + (size_t)(colb + row) * K + k0 + ((cs ^ s) << 3), bs + (size_t)cj * 8);
      }
    }
  };

  auto compute = [&](int b) {
    const unsigned short* as = lds + b * 4096;
    const unsigned short* bs = lds + 3 * 4096 + b * 4096;
    bf16x8 af[4], bfr[4];
    #pragma unroll
    for (int mb = 0; mb < 4; mb++) {
      int rowL = wrow + mb * 16 + lr;
      int s = (rowL & 3) ^ ((rowL >> 2) & 3);
      af[mb] = *(const bf16x8*)&as[rowL * 32 + ((lko ^ s) << 3)];
    }
    #pragma unroll
    for (int nb = 0; nb < 4; nb++) {
      int colL = wcol + nb * 16 + lr;
      int s = (colL & 3) ^ ((colL >> 2) & 3);
      bfr[nb] = *(const bf16x8*)&bs[colL * 32 + ((lko ^ s) << 3)];
    }
    #pragma unroll
    for (int mb = 0; mb < 4; mb++)
      #pragma unroll
      for (int nb = 0; nb < 4; nb++)
        acc[mb][nb] = __builtin_amdgcn_mfma_f32_16x16x32_bf16(af[mb], bfr[nb], acc[mb][nb], 0, 0, 0);
  };

  stage(0, 0);
  stage(32, 1);
  wait_vmcnt<LPT>();
  __builtin_amdgcn_sched_barrier(0);
  __builtin_amdgcn_s_barrier();
  #pragma unroll
  for (int s = 0; s < NS; s++) {
    if (s + 2 < NS) stage((s + 2) * 32, (s + 2) % 3);
    compute(s % 3);
    if (s + 1 < NS) {
      if (s + 2 < NS) wait_vmcnt<LPT>();
      else            wait_vmcnt<0>();
      __builtin_amdgcn_sched_barrier(0);
      __builtin_amdgcn_s_barrier();
    }
  }

  __syncthreads();
  unsigned short* Cs = lds;                // [128][128]
  const int orow = lko * 4;
  #pragma unroll
  for (int mb = 0; mb < 4; mb++) {
    #pragma unroll
    for (int i = 0; i < 4; i++) {
      int row = wrow + mb * 16 + orow + i;
      int sw = (row & 7) << 3;
      #pragma unroll
      for (int nb = 0; nb < 4; nb++) {
        int col = wcol + nb * 16 + lr;
        Cs[row * 128 + (col ^ sw)] = f2bf(acc[mb][nb][i] + biasv[colb + col]);
      }
    }
  }
  __syncthreads();
  unsigned short* Cout = bx ? xrt : xl;    // compact [NN][128] each
  #pragma unroll
  for (int it = 0; it < 8; it++) {
    int off = it * 256 + tid;
    int row = off >> 4, jb = off & 15;
    int grow = row0 + row;
    if (grow < M) {
      int idx = row * 128 + ((jb * 8) ^ ((row & 7) << 3));
      *(u16x8*)&Cout[(size_t)grow * 128 + jb * 8] = *(const u16x8*)&Cs[idx];
    }
  }
}

// ---- per-(dst,rel) counts only (deg derived in scans) ----
__global__ void k_deg(const int* __restrict__ ei, const int* __restrict__ et,
                      int* __restrict__ cnt2) {
  int e = blockIdx.x * 256 + threadIdx.x;
  if (e < NE) atomicAdd(&cnt2[ei[NE + e] * NREL + et[e]], 1);
}

__device__ __forceinline__ int node_deg(const int* cnt2, int n) {
  const int4* p = (const int4*)(cnt2 + n * NREL);
  int4 a = p[0], b = p[1];
  return a.x + a.y + a.z + a.w + b.x + b.y + b.z + b.w;
}

__global__ void k_scan_a(const int* __restrict__ cnt2, int* __restrict__ parts) {
  __shared__ int lds[256];
  int t = threadIdx.x;
  int base = blockIdx.x * 1024 + t * 4;
  int s = 0;
  #pragma unroll
  for (int j = 0; j < 4; j++) s += (base + j < NN) ? node_deg(cnt2, base + j) : 0;
  lds[t] = s;
  __syncthreads();
  for (int st = 128; st > 0; st >>= 1) {
    if (t < st) lds[t] += lds[t + st];
    __syncthreads();
  }
  if (t == 0) parts[blockIdx.x] = lds[0];
}

__global__ void k_scan_b(int* __restrict__ parts) {
  int t = threadIdx.x;   // 64 threads
  int v = (t < NCHUNKS) ? parts[t] : 0;
  int x = v;
  #pragma unroll
  for (int off = 1; off < 64; off <<= 1) {
    int y = __shfl_up(x, off, 64);
    if (t >= off) x += y;
  }
  if (t < NCHUNKS) parts[t] = x - v;
}

__global__ void k_scan_c(const int* __restrict__ cnt2, const int* __restrict__ parts,
                         int* __restrict__ rowptr) {
  __shared__ int lds[256];
  int t = threadIdx.x;
  int base = blockIdx.x * 1024 + t * 4;
  int v[4];
  int s = 0;
  #pragma unroll
  for (int j = 0; j < 4; j++) { v[j] = (base + j < NN) ? node_deg(cnt2, base + j) : 0; s += v[j]; }
  lds[t] = s;
  __syncthreads();
  for (int st = 1; st < 256; st <<= 1) {
    int add = (t >= st) ? lds[t - st] : 0;
    __syncthreads();
    lds[t] += add;
    __syncthreads();
  }
  int excl = lds[t] - s;
  int off = parts[blockIdx.x];
  int run = 0;
  #pragma unroll
  for (int j = 0; j < 4; j++) {
    run += v[j];
    if (base + j < NN) rowptr[base + j + 1] = off + excl + run;
  }
  if (blockIdx.x == 0 && t == 0) rowptr[0] = 0;
}

__global__ void k_scatter(const int* __restrict__ ei, const int* __restrict__ et,
                          const int* __restrict__ rowptr, const int* __restrict__ cnt2,
                          int* __restrict__ cursor, int* __restrict__ csr,
                          float* __restrict__ wgt) {
  int e = blockIdx.x * 256 + threadIdx.x;
  if (e < NE) {
    int d = ei[NE + e];
    int r = et[e];
    int pos = atomicAdd(&cursor[d], 1);
    int slot = rowptr[d] + pos;
    csr[slot] = ei[e] | (r << 20);
    wgt[slot] = 1.0f / (float)cnt2[d * NREL + r];
  }
}

// ---- RGCN aggregation: half-wave per dst, masked batch-16 ----
__global__ __launch_bounds__(256)
void k_rgcn(const unsigned short* __restrict__ xr, const int* __restrict__ csr2,
            const float* __restrict__ wgt, const int* __restrict__ rowptr,
            unsigned short* __restrict__ agg) {
  int wpair = (blockIdx.x * 256 + threadIdx.x) >> 6;
  int lane = threadIdx.x & 63;
  int hb = lane & 32;
  int l = lane & 31;
  int wid = wpair * 2 + (hb >> 5);
  if (wid >= NN) return;
  int c0 = l * 4;
  float a0 = 0.f, a1 = 0.f, a2 = 0.f, a3 = 0.f;
  int beg = rowptr[wid], end = rowptr[wid + 1];
  for (int j0 = beg; j0 < end; j0 += 32) {
    int nv = end - j0; if (nv > 32) nv = 32;
    int pk = (l < nv) ? csr2[j0 + l] : 0;
    float wk = (l < nv) ? wgt[j0 + l] : 0.f;
    for (int t = 0; t < nv; t += 16) {
      uint2 wv[16]; float wz[16];
      #pragma unroll
      for (int z = 0; z < 16; z++) {
        int p = __shfl(pk, hb + t + z, 64);
        wz[z] = __shfl(wk, hb + t + z, 64);
        if (t + z < nv) {
          size_t off = (size_t)(p & 0xFFFFF) * XRLD + (p >> 20) * H1 + c0;
          wv[z] = *(const uint2*)(xr + off);
        } else {
          wv[z] = make_uint2(0, 0);
        }
      }
      #pragma unroll
      for (int z = 0; z < 16; z++) {
        a0 += wz[z] * bf2f((unsigned short)(wv[z].x & 0xffff));
        a1 += wz[z] * bf2f((unsigned short)(wv[z].x >> 16));
        a2 += wz[z] * bf2f((unsigned short)(wv[z].y & 0xffff));
        a3 += wz[z] * bf2f((unsigned short)(wv[z].y >> 16));
      }
    }
  }
  uint2 packed;
  packed.x = (uint32_t)f2bf(a0) | ((uint32_t)f2bf(a1) << 16);
  packed.y = (uint32_t)f2bf(a2) | ((uint32_t)f2bf(a3) << 16);
  *(uint2*)&agg[(size_t)wid * H1 + c0] = packed;
}

// ---- GATv2: half-wave per dst, compact xl gathers, masked batch-16 ----
__global__ __launch_bounds__(256)
void k_gat(const unsigned short* __restrict__ xl, const unsigned short* __restrict__ xrt,
           const int* __restrict__ csr2, const int* __restrict__ rowptr,
           const float* __restrict__ att, const float* __restrict__ bias2,
           float* __restrict__ out) {
  int wpair = (blockIdx.x * 256 + threadIdx.x) >> 6;
  int lane = threadIdx.x & 63;
  int hb = lane & 32;
  int l = lane & 31;
  int wid = wpair * 2 + (hb >> 5);
  if (wid >= NN) return;
  int c0 = l * 4;
  float4 at = *(const float4*)(att + c0);
  uint2 wr2 = *(const uint2*)(xrt + (size_t)wid * 128 + c0);
  float xr0 = bf2f((unsigned short)(wr2.x & 0xffff));
  float xr1 = bf2f((unsigned short)(wr2.x >> 16));
  float xr2 = bf2f((unsigned short)(wr2.y & 0xffff));
  float xr3 = bf2f((unsigned short)(wr2.y >> 16));
  uint2 wv0 = *(const uint2*)(xl + (size_t)wid * 128 + c0);
  float v0 = bf2f((unsigned short)(wv0.x & 0xffff));
  float v1 = bf2f((unsigned short)(wv0.x >> 16));
  float v2 = bf2f((unsigned short)(wv0.y & 0xffff));
  float v3 = bf2f((unsigned short)(wv0.y >> 16));
  float ep = lrelu(v0 + xr0) * at.x + lrelu(v1 + xr1) * at.y +
             lrelu(v2 + xr2) * at.z + lrelu(v3 + xr3) * at.w;
  #pragma unroll
  for (int off = 16; off > 0; off >>= 1) ep += __shfl_xor(ep, off, 64);
  float m = ep, s = 1.f, o0 = v0, o1 = v1, o2 = v2, o3 = v3;
  int beg = rowptr[wid], end = rowptr[wid + 1];
  for (int j0 = beg; j0 < end; j0 += 32) {
    int nv = end - j0; if (nv > 32) nv = 32;
    int pk = (l < nv) ? csr2[j0 + l] : 0;
    for (int t = 0; t < nv; t += 16) {
      float u0[16], u1[16], u2[16], u3[16], p[16];
      #pragma unroll
      for (int z = 0; z < 16; z++) {
        int src = __shfl(pk, hb + t + z, 64) & 0xFFFFF;
        uint2 wu;
        if (t + z < nv) wu = *(const uint2*)(xl + (size_t)src * 128 + c0);
        else            wu = make_uint2(0, 0);
        u0[z] = bf2f((unsigned short)(wu.x & 0xffff));
        u1[z] = bf2f((unsigned short)(wu.x >> 16));
        u2[z] = bf2f((unsigned short)(wu.y & 0xffff));
        u3[z] = bf2f((unsigned short)(wu.y >> 16));
      }
      #pragma unroll
      for (int z = 0; z < 16; z++)
        p[z] = lrelu(u0[z] + xr0) * at.x + lrelu(u1[z] + xr1) * at.y +
               lrelu(u2[z] + xr2) * at.z + lrelu(u3[z] + xr3) * at.w;
      #pragma unroll
      for (int off = 16; off > 0; off >>= 1) {
        #pragma unroll
        for (int z = 0; z < 16; z++) p[z] += __shfl_xor(p[z], off, 64);
      }
      #pragma unroll
      for (int z = 0; z < 16; z++) if (t + z >= nv) p[z] = -1e30f;
      float pm = p[0];
      #pragma unroll
      for (int z = 1; z < 16; z++) pm = fmaxf(pm, p[z]);
      float mn = fmaxf(m, pm);
      float sc = __expf(m - mn);
      float e[16];
      #pragma unroll
      for (int z = 0; z < 16; z++) e[z] = __expf(p[z] - mn);
      float es = 0.f, e0 = 0.f, e1 = 0.f, e2 = 0.f, e3 = 0.f;
      #pragma unroll
      for (int z = 0; z < 16; z++) {
        es += e[z]; e0 += e[z] * u0[z]; e1 += e[z] * u1[z];
        e2 += e[z] * u2[z]; e3 += e[z] * u3[z];
      }
      s = s * sc + es;
      o0 = o0 * sc + e0; o1 = o1 * sc + e1;
      o2 = o2 * sc + e2; o3 = o3 * sc + e3;
      m = mn;
    }
  }
  float inv = 1.f / s;
  float4 b2 = *(const float4*)(bias2 + c0);
  float4 res = make_float4(o0 * inv + b2.x, o1 * inv + b2.y,
                           o2 * inv + b2.z, o3 * inv + b2.w);
  *(float4*)&out[(size_t)wid * H1 + c0] = res;
}

extern "C" void kernel_launch(void* const* d_in, const int* in_sizes, int n_in,
                              void* d_out, int out_size, void* d_ws, size_t ws_size,
                              hipStream_t stream) {
  const float* nf    = (const float*)d_in[0];
  const int*   ei    = (const int*)d_in[1];
  const int*   et    = (const int*)d_in[3];
  const float* basis = (const float*)d_in[4];
  const float* comp  = (const float*)d_in[5];
  const float* root  = (const float*)d_in[6];
  const float* bias1 = (const float*)d_in[7];
  const float* w_l   = (const float*)d_in[8];
  const float* w_r   = (const float*)d_in[9];
  const float* att   = (const float*)d_in[10];
  const float* bias2 = (const float*)d_in[11];
  float* out = (float*)d_out;

  char* ws = (char*)d_ws;
  unsigned short* xr_bf  = (unsigned short*)ws;                    // [NN][1024] 102.4 MB
  unsigned short* nf_bf  = (unsigned short*)(ws + 102400000);      // [NN][256]  25.6 MB
  unsigned short* wrb_t  = (unsigned short*)(ws + 128000000);      // [1024][256]
  unsigned short* btf    = (unsigned short*)(ws + 128524288);      // [256][384] bf16
  float*          biasv  = (float*)(ws + 128720896);               // [256]
  unsigned short* agg_bf = (unsigned short*)(ws + 128721920);      // [NN][128] bf16
  int*            cursor = (int*)(ws + 141521920);                 // [NN]
  int*            cnt2   = cursor + NN;                            // [NN*8]
  int*            rowptr = cnt2 + NN * NREL;                       // [NN+1]
  int*            csr    = rowptr + NN + 1;                        // [NE]
  int*            parts  = csr + NE;                               // [64]
  float*          wgt    = (float*)(parts + 64);                   // [NE]
  // overlays into xr region (dead after k_rgcn): compact split outputs
  unsigned short* xl_bf  = (unsigned short*)ws;                    // [NN][128] 12.8 MB
  unsigned short* xrt_bf = (unsigned short*)(ws + 12800000);       // [NN][128] 12.8 MB

  hipMemsetAsync(cursor, 0, (1 + NREL) * NN * sizeof(int), stream);

  k_cast<<<(NN * GD / 8) / 256, 256, 0, stream>>>(nf, nf_bf);
  k_wr<<<(XRLD * GD) / 256, 256, 0, stream>>>(basis, comp, wrb_t);
  k_prep2<<<256, 256, 0, stream>>>(root, w_l, w_r, bias1, btf, biasv);

  const int GY128 = (NN + 127) / 128;   // 391
  k_mgemm<256, 4><<<8 * GY128, 256, 49152, stream>>>(
      nf_bf, wrb_t, xr_bf, NN, XRLD, 8);

  k_deg<<<(NE + 255) / 256, 256, 0, stream>>>(ei, et, cnt2);
  k_scan_a<<<NCHUNKS, 256, 0, stream>>>(cnt2, parts);
  k_scan_b<<<1, 64, 0, stream>>>(parts);
  k_scan_c<<<NCHUNKS, 256, 0, stream>>>(cnt2, parts, rowptr);
  k_scatter<<<(NE + 255) / 256, 256, 0, stream>>>(ei, et, rowptr, cnt2, cursor, csr, wgt);

  k_rgcn<<<(NN + 7) / 8, 256, 0, stream>>>(xr_bf, csr, wgt, rowptr, agg_bf);

  k_fused<<<2 * GY128, 256, 49152, stream>>>(agg_bf, nf_bf, btf, biasv, xl_bf, xrt_bf, NN);

  k_gat<<<(NN + 7) / 8, 256, 0, stream>>>(xl_bf, xrt_bf, csr, rowptr, att, bias2, out);
}

// Round 17
// 241.256 us; speedup vs baseline: 1.0605x; 1.0605x over previous
//
#include <hip/hip_runtime.h>
#include <hip/hip_bf16.h>
#include <cstdint>
#include <cstddef>

#define NN 50000
#define NE 500000
#define GD 256
#define H1 128
#define H2 128
#define NREL 8
#define NBASES 30
#define XRLD (NREL * H1)   // 1024
#define NCHUNKS ((NN + 1023) / 1024)  // 49

typedef __attribute__((ext_vector_type(8))) short bf16x8;
typedef __attribute__((ext_vector_type(4))) float f32x4;
typedef __attribute__((ext_vector_type(8))) unsigned short u16x8;
typedef __attribute__((ext_vector_type(4))) unsigned int u32x4;

__device__ __forceinline__ float lrelu(float x) { return x > 0.f ? x : 0.2f * x; }

// manual RTNE (no NaN path) — proven fastest (R13 vs R14 A/B)
__device__ __forceinline__ unsigned short f2bf(float x) {
  union { float f; uint32_t u; } v; v.f = x;
  uint32_t r = v.u + 0x7FFF + ((v.u >> 16) & 1);
  return (unsigned short)(r >> 16);
}
__device__ __forceinline__ float bf2f(unsigned short u) {
  union { uint32_t u; float f; } v; v.u = ((uint32_t)u) << 16;
  return v.f;
}

template <int N>
__device__ __forceinline__ void wait_vmcnt() {
  asm volatile("s_waitcnt vmcnt(%0)" :: "n"(N) : "memory");
}

__device__ __forceinline__ void gload_lds(const unsigned short* gp, unsigned short* lp) {
  __builtin_amdgcn_global_load_lds(
      (const __attribute__((address_space(1))) void*)gp,
      (__attribute__((address_space(3))) void*)lp, 16, 0, 0);
}

// ---- cast nf fp32 -> bf16 ----
__global__ void k_cast(const float* __restrict__ in, unsigned short* __restrict__ out) {
  int i = blockIdx.x * 256 + threadIdx.x;
  const float4* p = (const float4*)(in + (size_t)i * 8);
  float4 a = p[0], b = p[1];
  u16x8 r;
  r[0] = f2bf(a.x); r[1] = f2bf(a.y); r[2] = f2bf(a.z); r[3] = f2bf(a.w);
  r[4] = f2bf(b.x); r[5] = f2bf(b.y); r[6] = f2bf(b.z); r[7] = f2bf(b.w);
  *(u16x8*)(out + (size_t)i * 8) = r;
}

// ---- wrb_t[n][k] bf16 [1024][256] ----
__global__ void k_wr(const float* __restrict__ basis, const float* __restrict__ comp,
                     unsigned short* __restrict__ wrb_t) {
  int idx = blockIdx.x * 256 + threadIdx.x;
  int n = idx >> 8;
  int k = idx & 255;
  int r = n >> 7, o = n & 127;
  float acc = 0.f;
  #pragma unroll
  for (int b = 0; b < NBASES; b++)
    acc += comp[r * NBASES + b] * basis[((size_t)b * GD + k) * H1 + o];
  wrb_t[idx] = f2bf(acc);
}

// ---- prep2: one block per column c. LDS-stage wcat[:,c], parallel dots. ----
__global__ __launch_bounds__(256)
void k_prep2(const float* __restrict__ root, const float* __restrict__ w_l,
             const float* __restrict__ w_r, const float* __restrict__ bias1,
             unsigned short* __restrict__ btf, float* __restrict__ biasv) {
  __shared__ float wcol[128];
  __shared__ float red[128];
  int c = blockIdx.x;        // 0..255
  int t = threadIdx.x;       // 0..255
  if (t < 128) {
    float v = (c < H2) ? w_l[t * H2 + c] : w_r[t * H2 + (c - H2)];
    wcol[t] = v;
    btf[c * 384 + t] = f2bf(v);
  }
  __syncthreads();
  const float4* rp = (const float4*)(root + (size_t)t * H1);
  float acc = 0.f;
  #pragma unroll
  for (int j4 = 0; j4 < 32; j4++) {
    float4 r4 = rp[j4];
    acc += r4.x * wcol[j4 * 4 + 0] + r4.y * wcol[j4 * 4 + 1] +
           r4.z * wcol[j4 * 4 + 2] + r4.w * wcol[j4 * 4 + 3];
  }
  btf[c * 384 + 128 + t] = f2bf(acc);
  if (t < 128) red[t] = bias1[t] * wcol[t];
  __syncthreads();
  for (int st = 64; st > 0; st >>= 1) {
    if (t < st) red[t] += red[t + st];
    __syncthreads();
  }
  if (t == 0) biasv[c] = red[0];
}

// ---- xr GEMM: wave tile 64x64 (WM=4), block 128x128, 3-buf BK=32, counted vmcnt ----
// C-store uses NONTEMPORAL (xr is 102MB streaming output, never L2-resident).
template <int K, int WM>
__global__ __launch_bounds__(256, 3)
void k_mgemm(const unsigned short* __restrict__ A, const unsigned short* __restrict__ Bt,
             unsigned short* __restrict__ C, int M, int N, int gx) {
  constexpr int BM = WM * 32;
  constexpr int ACH = BM * 4;
  constexpr int TCH = ACH + 512;
  constexpr int LPT = TCH / 256;
  constexpr int NS = K / 32;
  constexpr int ABUF = BM * 32;
  constexpr int BBUF = 128 * 32;
  extern __shared__ unsigned short lds[];
  const int tid = threadIdx.x;
  const int lane = tid & 63;
  const int wave = tid >> 6;

  const int nwg = gridDim.x;
  const int q = nwg >> 3, r = nwg & 7;
  const int xcd = blockIdx.x & 7, bi = blockIdx.x >> 3;
  const int wg = (xcd < r ? xcd * (q + 1) : r * (q + 1) + (xcd - r) * q) + bi;
  const int bx = wg % gx;
  const int by = wg / gx;
  const int row0 = by * BM;
  const int colb = bx * 128;
  const int wcol = (wave & 1) * 64;
  const int wrow = (wave >> 1) * (WM * 16);
  const int lr = lane & 15;
  const int lko = lane >> 4;

  f32x4 acc[WM][4];
  #pragma unroll
  for (int i = 0; i < WM; i++)
    #pragma unroll
    for (int j = 0; j < 4; j++) acc[i][j] = (f32x4){0.f, 0.f, 0.f, 0.f};

  auto stage = [&](int k0, int b) {
    unsigned short* as = lds + b * ABUF;
    unsigned short* bs = lds + 3 * ABUF + b * BBUF;
    #pragma unroll
    for (int it = 0; it < LPT; it++) {
      int ci = it * 256 + tid;
      if (ci < ACH) {
        int row = ci >> 2, cs = ci & 3;
        int s = (row & 3) ^ ((row >> 2) & 3);
        int gm = row0 + row; if (gm >= M) gm = M - 1;
        gload_lds(A + (size_t)gm * K + k0 + ((cs ^ s) << 3), as + (size_t)ci * 8);
      } else {
        int cj = ci - ACH;
        int row = cj >> 2, cs = cj & 3;
        int s = (row & 3) ^ ((row >> 2) & 3);
        gload_lds(Bt + (size_t)(colb + row) * K + k0 + ((cs ^ s) << 3), bs + (size_t)cj * 8);
      }
    }
  };

  auto compute = [&](int b) {
    const unsigned short* as = lds + b * ABUF;
    const unsigned short* bs = lds + 3 * ABUF + b * BBUF;
    bf16x8 af[WM], bfr[4];
    #pragma unroll
    for (int mb = 0; mb < WM; mb++) {
      int rowL = wrow + mb * 16 + lr;
      int s = (rowL & 3) ^ ((rowL >> 2) & 3);
      af[mb] = *(const bf16x8*)&as[rowL * 32 + ((lko ^ s) << 3)];
    }
    #pragma unroll
    for (int nb = 0; nb < 4; nb++) {
      int colL = wcol + nb * 16 + lr;
      int s = (colL & 3) ^ ((colL >> 2) & 3);
      bfr[nb] = *(const bf16x8*)&bs[colL * 32 + ((lko ^ s) << 3)];
    }
    #pragma unroll
    for (int mb = 0; mb < WM; mb++)
      #pragma unroll
      for (int nb = 0; nb < 4; nb++)
        acc[mb][nb] = __builtin_amdgcn_mfma_f32_16x16x32_bf16(af[mb], bfr[nb], acc[mb][nb], 0, 0, 0);
  };

  stage(0, 0);
  stage(32, 1);
  wait_vmcnt<LPT>();
  __builtin_amdgcn_sched_barrier(0);
  __builtin_amdgcn_s_barrier();
  #pragma unroll
  for (int s = 0; s < NS; s++) {
    if (s + 2 < NS) stage((s + 2) * 32, (s + 2) % 3);
    compute(s % 3);
    if (s + 1 < NS) {
      if (s + 2 < NS) wait_vmcnt<LPT>();
      else            wait_vmcnt<0>();
      __builtin_amdgcn_sched_barrier(0);
      __builtin_amdgcn_s_barrier();
    }
  }

  __syncthreads();
  unsigned short* Cs = lds;                // [BM][128]
  const int orow = lko * 4;
  #pragma unroll
  for (int mb = 0; mb < WM; mb++) {
    #pragma unroll
    for (int i = 0; i < 4; i++) {
      int row = wrow + mb * 16 + orow + i;
      int sw = (row & 7) << 3;
      #pragma unroll
      for (int nb = 0; nb < 4; nb++) {
        int col = wcol + nb * 16 + lr;
        Cs[row * 128 + (col ^ sw)] = f2bf(acc[mb][nb][i]);
      }
    }
  }
  __syncthreads();
  #pragma unroll
  for (int it = 0; it < BM / 16; it++) {
    int off = it * 256 + tid;
    int row = off >> 4, jb = off & 15;
    int grow = row0 + row;
    if (grow < M) {
      int idx = row * 128 + ((jb * 8) ^ ((row & 7) << 3));
      u32x4 val = *(const u32x4*)&Cs[idx];
      __builtin_nontemporal_store(val, (u32x4*)&C[(size_t)grow * N + colb + jb * 8]);
    }
  }
}

// ---- fused GEMM: [xl|xrt] = [agg|nf] @ btf^T + biasv; split compact outputs ----
// outputs are gathered immediately by k_gat -> keep cacheable (NO nt store).
__global__ __launch_bounds__(256, 3)
void k_fused(const unsigned short* __restrict__ A1, const unsigned short* __restrict__ A2,
             const unsigned short* __restrict__ Bt, const float* __restrict__ biasv,
             unsigned short* __restrict__ xl, unsigned short* __restrict__ xrt, int M) {
  constexpr int K = 384, NS = 12, LPT = 4;
  extern __shared__ unsigned short lds[];
  const int tid = threadIdx.x;
  const int lane = tid & 63;
  const int wave = tid >> 6;

  const int nwg = gridDim.x;
  const int q = nwg >> 3, r = nwg & 7;
  const int xcd = blockIdx.x & 7, bi = blockIdx.x >> 3;
  const int wg = (xcd < r ? xcd * (q + 1) : r * (q + 1) + (xcd - r) * q) + bi;
  const int bx = wg & 1;
  const int by = wg >> 1;
  const int row0 = by * 128;
  const int colb = bx * 128;
  const int wcol = (wave & 1) * 64;
  const int wrow = (wave >> 1) * 64;
  const int lr = lane & 15;
  const int lko = lane >> 4;

  f32x4 acc[4][4];
  #pragma unroll
  for (int i = 0; i < 4; i++)
    #pragma unroll
    for (int j = 0; j < 4; j++) acc[i][j] = (f32x4){0.f, 0.f, 0.f, 0.f};

  auto stage = [&](int k0, int b) {
    unsigned short* as = lds + b * 4096;
    unsigned short* bs = lds + 3 * 4096 + b * 4096;
    #pragma unroll
    for (int it = 0; it < LPT; it++) {
      int ci = it * 256 + tid;
      if (ci < 512) {
        int row = ci >> 2, cs = ci & 3;
        int s = (row & 3) ^ ((row >> 2) & 3);
        int gm = row0 + row; if (gm >= M) gm = M - 1;
        const unsigned short* gp;
        if (k0 < 128) gp = A1 + (size_t)gm * 128 + k0 + ((cs ^ s) << 3);
        else          gp = A2 + (size_t)gm * 256 + (k0 - 128) + ((cs ^ s) << 3);
        gload_lds(gp, as + (size_t)ci * 8);
      } else {
        int cj = ci - 512;
        int row = cj >> 2, cs = cj & 3;
        int s = (row & 3) ^ ((row >> 2) & 3);
        gload_lds(Bt + (size_t)(colb + row) * K + k0 + ((cs ^ s) << 3), bs + (size_t)cj * 8);
      }
    }
  };

  auto compute = [&](int b) {
    const unsigned short* as = lds + b * 4096;
    const unsigned short* bs = lds + 3 * 4096 + b * 4096;
    bf16x8 af[4], bfr[4];
    #pragma unroll
    for (int mb = 0; mb < 4; mb++) {
      int rowL = wrow + mb * 16 + lr;
      int s = (rowL & 3) ^ ((rowL >> 2) & 3);
      af[mb] = *(const bf16x8*)&as[rowL * 32 + ((lko ^ s) << 3)];
    }
    #pragma unroll
    for (int nb = 0; nb < 4; nb++) {
      int colL = wcol + nb * 16 + lr;
      int s = (colL & 3) ^ ((colL >> 2) & 3);
      bfr[nb] = *(const bf16x8*)&bs[colL * 32 + ((lko ^ s) << 3)];
    }
    #pragma unroll
    for (int mb = 0; mb < 4; mb++)
      #pragma unroll
      for (int nb = 0; nb < 4; nb++)
        acc[mb][nb] = __builtin_amdgcn_mfma_f32_16x16x32_bf16(af[mb], bfr[nb], acc[mb][nb], 0, 0, 0);
  };

  stage(0, 0);
  stage(32, 1);
  wait_vmcnt<LPT>();
  __builtin_amdgcn_sched_barrier(0);
  __builtin_amdgcn_s_barrier();
  #pragma unroll
  for (int s = 0; s < NS; s++) {
    if (s + 2 < NS) stage((s + 2) * 32, (s + 2) % 3);
    compute(s % 3);
    if (s + 1 < NS) {
      if (s + 2 < NS) wait_vmcnt<LPT>();
      else            wait_vmcnt<0>();
      __builtin_amdgcn_sched_barrier(0);
      __builtin_amdgcn_s_barrier();
    }
  }

  __syncthreads();
  unsigned short* Cs = lds;                // [128][128]
  const int orow = lko * 4;
  #pragma unroll
  for (int mb = 0; mb < 4; mb++) {
    #pragma unroll
    for (int i = 0; i < 4; i++) {
      int row = wrow + mb * 16 + orow + i;
      int sw = (row & 7) << 3;
      #pragma unroll
      for (int nb = 0; nb < 4; nb++) {
        int col = wcol + nb * 16 + lr;
        Cs[row * 128 + (col ^ sw)] = f2bf(acc[mb][nb][i] + biasv[colb + col]);
      }
    }
  }
  __syncthreads();
  unsigned short* Cout = bx ? xrt : xl;    // compact [NN][128] each
  #pragma unroll
  for (int it = 0; it < 8; it++) {
    int off = it * 256 + tid;
    int row = off >> 4, jb = off & 15;
    int grow = row0 + row;
    if (grow < M) {
      int idx = row * 128 + ((jb * 8) ^ ((row & 7) << 3));
      *(u16x8*)&Cout[(size_t)grow * 128 + jb * 8] = *(const u16x8*)&Cs[idx];
    }
  }
}

// ---- per-(dst,rel) counts only (deg derived in scans) ----
__global__ void k_deg(const int* __restrict__ ei, const int* __restrict__ et,
                      int* __restrict__ cnt2) {
  int e = blockIdx.x * 256 + threadIdx.x;
  if (e < NE) atomicAdd(&cnt2[ei[NE + e] * NREL + et[e]], 1);
}

__device__ __forceinline__ int node_deg(const int* cnt2, int n) {
  const int4* p = (const int4*)(cnt2 + n * NREL);
  int4 a = p[0], b = p[1];
  return a.x + a.y + a.z + a.w + b.x + b.y + b.z + b.w;
}

__global__ void k_scan_a(const int* __restrict__ cnt2, int* __restrict__ parts) {
  __shared__ int lds[256];
  int t = threadIdx.x;
  int base = blockIdx.x * 1024 + t * 4;
  int s = 0;
  #pragma unroll
  for (int j = 0; j < 4; j++) s += (base + j < NN) ? node_deg(cnt2, base + j) : 0;
  lds[t] = s;
  __syncthreads();
  for (int st = 128; st > 0; st >>= 1) {
    if (t < st) lds[t] += lds[t + st];
    __syncthreads();
  }
  if (t == 0) parts[blockIdx.x] = lds[0];
}

__global__ void k_scan_b(int* __restrict__ parts) {
  int t = threadIdx.x;   // 64 threads
  int v = (t < NCHUNKS) ? parts[t] : 0;
  int x = v;
  #pragma unroll
  for (int off = 1; off < 64; off <<= 1) {
    int y = __shfl_up(x, off, 64);
    if (t >= off) x += y;
  }
  if (t < NCHUNKS) parts[t] = x - v;
}

__global__ void k_scan_c(const int* __restrict__ cnt2, const int* __restrict__ parts,
                         int* __restrict__ rowptr) {
  __shared__ int lds[256];
  int t = threadIdx.x;
  int base = blockIdx.x * 1024 + t * 4;
  int v[4];
  int s = 0;
  #pragma unroll
  for (int j = 0; j < 4; j++) { v[j] = (base + j < NN) ? node_deg(cnt2, base + j) : 0; s += v[j]; }
  lds[t] = s;
  __syncthreads();
  for (int st = 1; st < 256; st <<= 1) {
    int add = (t >= st) ? lds[t - st] : 0;
    __syncthreads();
    lds[t] += add;
    __syncthreads();
  }
  int excl = lds[t] - s;
  int off = parts[blockIdx.x];
  int run = 0;
  #pragma unroll
  for (int j = 0; j < 4; j++) {
    run += v[j];
    if (base + j < NN) rowptr[base + j + 1] = off + excl + run;
  }
  if (blockIdx.x == 0 && t == 0) rowptr[0] = 0;
}

__global__ void k_scatter(const int* __restrict__ ei, const int* __restrict__ et,
                          const int* __restrict__ rowptr, const int* __restrict__ cnt2,
                          int* __restrict__ cursor, int* __restrict__ csr,
                          float* __restrict__ wgt) {
  int e = blockIdx.x * 256 + threadIdx.x;
  if (e < NE) {
    int d = ei[NE + e];
    int r = et[e];
    int pos = atomicAdd(&cursor[d], 1);
    int slot = rowptr[d] + pos;
    csr[slot] = ei[e] | (r << 20);
    wgt[slot] = 1.0f / (float)cnt2[d * NREL + r];
  }
}

// ---- RGCN aggregation: half-wave per dst, masked batch-8 (R13-proven) ----
__global__ __launch_bounds__(256)
void k_rgcn(const unsigned short* __restrict__ xr, const int* __restrict__ csr2,
            const float* __restrict__ wgt, const int* __restrict__ rowptr,
            unsigned short* __restrict__ agg) {
  int wpair = (blockIdx.x * 256 + threadIdx.x) >> 6;
  int lane = threadIdx.x & 63;
  int hb = lane & 32;
  int l = lane & 31;
  int wid = wpair * 2 + (hb >> 5);
  if (wid >= NN) return;
  int c0 = l * 4;
  float a0 = 0.f, a1 = 0.f, a2 = 0.f, a3 = 0.f;
  int beg = rowptr[wid], end = rowptr[wid + 1];
  for (int j0 = beg; j0 < end; j0 += 32) {
    int nv = end - j0; if (nv > 32) nv = 32;
    int pk = (l < nv) ? csr2[j0 + l] : 0;
    float wk = (l < nv) ? wgt[j0 + l] : 0.f;
    for (int t = 0; t < nv; t += 8) {
      uint2 wv[8]; float wz[8];
      #pragma unroll
      for (int z = 0; z < 8; z++) {
        int p = __shfl(pk, hb + t + z, 64);
        wz[z] = __shfl(wk, hb + t + z, 64);
        if (t + z < nv) {
          size_t off = (size_t)(p & 0xFFFFF) * XRLD + (p >> 20) * H1 + c0;
          wv[z] = *(const uint2*)(xr + off);
        } else {
          wv[z] = make_uint2(0, 0);
        }
      }
      #pragma unroll
      for (int z = 0; z < 8; z++) {
        a0 += wz[z] * bf2f((unsigned short)(wv[z].x & 0xffff));
        a1 += wz[z] * bf2f((unsigned short)(wv[z].x >> 16));
        a2 += wz[z] * bf2f((unsigned short)(wv[z].y & 0xffff));
        a3 += wz[z] * bf2f((unsigned short)(wv[z].y >> 16));
      }
    }
  }
  uint2 packed;
  packed.x = (uint32_t)f2bf(a0) | ((uint32_t)f2bf(a1) << 16);
  packed.y = (uint32_t)f2bf(a2) | ((uint32_t)f2bf(a3) << 16);
  *(uint2*)&agg[(size_t)wid * H1 + c0] = packed;
}

// ---- GATv2: half-wave per dst, compact xl gathers, masked batch-8 (R13-proven) ----
__global__ __launch_bounds__(256)
void k_gat(const unsigned short* __restrict__ xl, const unsigned short* __restrict__ xrt,
           const int* __restrict__ csr2, const int* __restrict__ rowptr,
           const float* __restrict__ att, const float* __restrict__ bias2,
           float* __restrict__ out) {
  int wpair = (blockIdx.x * 256 + threadIdx.x) >> 6;
  int lane = threadIdx.x & 63;
  int hb = lane & 32;
  int l = lane & 31;
  int wid = wpair * 2 + (hb >> 5);
  if (wid >= NN) return;
  int c0 = l * 4;
  float4 at = *(const float4*)(att + c0);
  uint2 wr2 = *(const uint2*)(xrt + (size_t)wid * 128 + c0);
  float xr0 = bf2f((unsigned short)(wr2.x & 0xffff));
  float xr1 = bf2f((unsigned short)(wr2.x >> 16));
  float xr2 = bf2f((unsigned short)(wr2.y & 0xffff));
  float xr3 = bf2f((unsigned short)(wr2.y >> 16));
  uint2 wv0 = *(const uint2*)(xl + (size_t)wid * 128 + c0);
  float v0 = bf2f((unsigned short)(wv0.x & 0xffff));
  float v1 = bf2f((unsigned short)(wv0.x >> 16));
  float v2 = bf2f((unsigned short)(wv0.y & 0xffff));
  float v3 = bf2f((unsigned short)(wv0.y >> 16));
  float ep = lrelu(v0 + xr0) * at.x + lrelu(v1 + xr1) * at.y +
             lrelu(v2 + xr2) * at.z + lrelu(v3 + xr3) * at.w;
  #pragma unroll
  for (int off = 16; off > 0; off >>= 1) ep += __shfl_xor(ep, off, 64);
  float m = ep, s = 1.f, o0 = v0, o1 = v1, o2 = v2, o3 = v3;
  int beg = rowptr[wid], end = rowptr[wid + 1];
  for (int j0 = beg; j0 < end; j0 += 32) {
    int nv = end - j0; if (nv > 32) nv = 32;
    int pk = (l < nv) ? csr2[j0 + l] : 0;
    for (int t = 0; t < nv; t += 8) {
      float u0[8], u1[8], u2[8], u3[8], p[8];
      #pragma unroll
      for (int z = 0; z < 8; z++) {
        int src = __shfl(pk, hb + t + z, 64) & 0xFFFFF;
        uint2 wu;
        if (t + z < nv) wu = *(const uint2*)(xl + (size_t)src * 128 + c0);
        else            wu = make_uint2(0, 0);
        u0[z] = bf2f((unsigned short)(wu.x & 0xffff));
        u1[z] = bf2f((unsigned short)(wu.x >> 16));
        u2[z] = bf2f((unsigned short)(wu.y & 0xffff));
        u3[z] = bf2f((unsigned short)(wu.y >> 16));
      }
      #pragma unroll
      for (int z = 0; z < 8; z++)
        p[z] = lrelu(u0[z] + xr0) * at.x + lrelu(u1[z] + xr1) * at.y +
               lrelu(u2[z] + xr2) * at.z + lrelu(u3[z] + xr3) * at.w;
      #pragma unroll
      for (int off = 16; off > 0; off >>= 1) {
        #pragma unroll
        for (int z = 0; z < 8; z++) p[z] += __shfl_xor(p[z], off, 64);
      }
      #pragma unroll
      for (int z = 0; z < 8; z++) if (t + z >= nv) p[z] = -1e30f;
      float pm = p[0];
      #pragma unroll
      for (int z = 1; z < 8; z++) pm = fmaxf(pm, p[z]);
      float mn = fmaxf(m, pm);
      float sc = __expf(m - mn);
      float e[8];
      #pragma unroll
      for (int z = 0; z < 8; z++) e[z] = __expf(p[z] - mn);
      float es = 0.f, e0 = 0.f, e1 = 0.f, e2 = 0.f, e3 = 0.f;
      #pragma unroll
      for (int z = 0; z < 8; z++) {
        es += e[z]; e0 += e[z] * u0[z]; e1 += e[z] * u1[z];
        e2 += e[z] * u2[z]; e3 += e[z] * u3[z];
      }
      s = s * sc + es;
      o0 = o0 * sc + e0; o1 = o1 * sc + e1;
      o2 = o2 * sc + e2; o3 = o3 * sc + e3;
      m = mn;
    }
  }
  float inv = 1.f / s;
  float4 b2 = *(const float4*)(bias2 + c0);
  float4 res = make_float4(o0 * inv + b2.x, o1 * inv + b2.y,
                           o2 * inv + b2.z, o3 * inv + b2.w);
  *(float4*)&out[(size_t)wid * H1 + c0] = res;
}

extern "C" void kernel_launch(void* const* d_in, const int* in_sizes, int n_in,
                              void* d_out, int out_size, void* d_ws, size_t ws_size,
                              hipStream_t stream) {
  const float* nf    = (const float*)d_in[0];
  const int*   ei    = (const int*)d_in[1];
  const int*   et    = (const int*)d_in[3];
  const float* basis = (const float*)d_in[4];
  const float* comp  = (const float*)d_in[5];
  const float* root  = (const float*)d_in[6];
  const float* bias1 = (const float*)d_in[7];
  const float* w_l   = (const float*)d_in[8];
  const float* w_r   = (const float*)d_in[9];
  const float* att   = (const float*)d_in[10];
  const float* bias2 = (const float*)d_in[11];
  float* out = (float*)d_out;

  char* ws = (char*)d_ws;
  unsigned short* xr_bf  = (unsigned short*)ws;                    // [NN][1024] 102.4 MB
  unsigned short* nf_bf  = (unsigned short*)(ws + 102400000);      // [NN][256]  25.6 MB
  unsigned short* wrb_t  = (unsigned short*)(ws + 128000000);      // [1024][256]
  unsigned short* btf    = (unsigned short*)(ws + 128524288);      // [256][384] bf16
  float*          biasv  = (float*)(ws + 128720896);               // [256]
  unsigned short* agg_bf = (unsigned short*)(ws + 128721920);      // [NN][128] bf16
  int*            cursor = (int*)(ws + 141521920);                 // [NN]
  int*            cnt2   = cursor + NN;                            // [NN*8]
  int*            rowptr = cnt2 + NN * NREL;                       // [NN+1]
  int*            csr    = rowptr + NN + 1;                        // [NE]
  int*            parts  = csr + NE;                               // [64]
  float*          wgt    = (float*)(parts + 64);                   // [NE]
  // overlays into xr region (dead after k_rgcn): compact split outputs
  unsigned short* xl_bf  = (unsigned short*)ws;                    // [NN][128] 12.8 MB
  unsigned short* xrt_bf = (unsigned short*)(ws + 12800000);       // [NN][128] 12.8 MB

  hipMemsetAsync(cursor, 0, (1 + NREL) * NN * sizeof(int), stream);

  k_cast<<<(NN * GD / 8) / 256, 256, 0, stream>>>(nf, nf_bf);
  k_wr<<<(XRLD * GD) / 256, 256, 0, stream>>>(basis, comp, wrb_t);
  k_prep2<<<256, 256, 0, stream>>>(root, w_l, w_r, bias1, btf, biasv);

  const int GY128 = (NN + 127) / 128;   // 391
  k_mgemm<256, 4><<<8 * GY128, 256, 49152, stream>>>(
      nf_bf, wrb_t, xr_bf, NN, XRLD, 8);

  k_deg<<<(NE + 255) / 256, 256, 0, stream>>>(ei, et, cnt2);
  k_scan_a<<<NCHUNKS, 256, 0, stream>>>(cnt2, parts);
  k_scan_b<<<1, 64, 0, stream>>>(parts);
  k_scan_c<<<NCHUNKS, 256, 0, stream>>>(cnt2, parts, rowptr);
  k_scatter<<<(NE + 255) / 256, 256, 0, stream>>>(ei, et, rowptr, cnt2, cursor, csr, wgt);

  k_rgcn<<<(NN + 7) / 8, 256, 0, stream>>>(xr_bf, csr, wgt, rowptr, agg_bf);

  k_fused<<<2 * GY128, 256, 49152, stream>>>(agg_bf, nf_bf, btf, biasv, xl_bf, xrt_bf, NN);

  k_gat<<<(NN + 7) / 8, 256, 0, stream>>>(xl_bf, xrt_bf, csr, rowptr, att, bias2, out);
}

// Round 18
// 240.556 us; speedup vs baseline: 1.0636x; 1.0029x over previous
//
#include <hip/hip_runtime.h>
#include <hip/hip_bf16.h>
#include <cstdint>
#include <cstddef>

#define NN 50000
#define NE 500000
#define GD 256
#define H1 128
#define H2 128
#define NREL 8
#define NBASES 30
#define XRLD (NREL * H1)   // 1024
#define NCHUNKS ((NN + 1023) / 1024)  // 49

typedef __attribute__((ext_vector_type(8))) short bf16x8;
typedef __attribute__((ext_vector_type(4))) float f32x4;
typedef __attribute__((ext_vector_type(8))) unsigned short u16x8;
typedef __attribute__((ext_vector_type(4))) unsigned int u32x4;

__device__ __forceinline__ float lrelu(float x) { return x > 0.f ? x : 0.2f * x; }

// manual RTNE (no NaN path) — proven fastest (R13 vs R14 A/B)
__device__ __forceinline__ unsigned short f2bf(float x) {
  union { float f; uint32_t u; } v; v.f = x;
  uint32_t r = v.u + 0x7FFF + ((v.u >> 16) & 1);
  return (unsigned short)(r >> 16);
}
__device__ __forceinline__ float bf2f(unsigned short u) {
  union { uint32_t u; float f; } v; v.u = ((uint32_t)u) << 16;
  return v.f;
}

template <int N>
__device__ __forceinline__ void wait_vmcnt() {
  asm volatile("s_waitcnt vmcnt(%0)" :: "n"(N) : "memory");
}

__device__ __forceinline__ void gload_lds(const unsigned short* gp, unsigned short* lp) {
  __builtin_amdgcn_global_load_lds(
      (const __attribute__((address_space(1))) void*)gp,
      (__attribute__((address_space(3))) void*)lp, 16, 0, 0);
}

// ---- merged prep: block-partitioned (block-uniform branches, no divergence) ----
#define PRE_CAST_BLKS 6250                       // NN*GD/8 / 256
#define PRE_WR_BLKS   1024                       // 1024*256 / 256
#define PRE_ALL_BLKS  (PRE_CAST_BLKS + PRE_WR_BLKS + 256)   // 7530
__global__ __launch_bounds__(256)
void k_pre3(const float* __restrict__ nf, unsigned short* __restrict__ nf_bf,
            const float* __restrict__ basis, const float* __restrict__ comp,
            unsigned short* __restrict__ wrb_t,
            const float* __restrict__ root, const float* __restrict__ w_l,
            const float* __restrict__ w_r, const float* __restrict__ bias1,
            unsigned short* __restrict__ btf, float* __restrict__ biasv) {
  __shared__ float wcol[128];
  __shared__ float red[128];
  const int b = blockIdx.x;
  const int t = threadIdx.x;
  if (b < PRE_CAST_BLKS) {
    // fp32 -> bf16 cast, 8 elems/thread
    int i = b * 256 + t;
    const float4* p = (const float4*)(nf + (size_t)i * 8);
    float4 a = p[0], bb = p[1];
    u16x8 r;
    r[0] = f2bf(a.x); r[1] = f2bf(a.y); r[2] = f2bf(a.z); r[3] = f2bf(a.w);
    r[4] = f2bf(bb.x); r[5] = f2bf(bb.y); r[6] = f2bf(bb.z); r[7] = f2bf(bb.w);
    *(u16x8*)(nf_bf + (size_t)i * 8) = r;
  } else if (b < PRE_CAST_BLKS + PRE_WR_BLKS) {
    // wrb_t[n][k] = sum_b comp[r][b]*basis[b][k][o]
    int idx = (b - PRE_CAST_BLKS) * 256 + t;
    int n = idx >> 8;
    int k = idx & 255;
    int r = n >> 7, o = n & 127;
    float acc = 0.f;
    #pragma unroll
    for (int bs = 0; bs < NBASES; bs++)
      acc += comp[r * NBASES + bs] * basis[((size_t)bs * GD + k) * H1 + o];
    wrb_t[idx] = f2bf(acc);
  } else {
    // prep2: one block per output column c
    int c = b - (PRE_CAST_BLKS + PRE_WR_BLKS);   // 0..255
    if (t < 128) {
      float v = (c < H2) ? w_l[t * H2 + c] : w_r[t * H2 + (c - H2)];
      wcol[t] = v;
      btf[c * 384 + t] = f2bf(v);
    }
    __syncthreads();
    const float4* rp = (const float4*)(root + (size_t)t * H1);
    float acc = 0.f;
    #pragma unroll
    for (int j4 = 0; j4 < 32; j4++) {
      float4 r4 = rp[j4];
      acc += r4.x * wcol[j4 * 4 + 0] + r4.y * wcol[j4 * 4 + 1] +
             r4.z * wcol[j4 * 4 + 2] + r4.w * wcol[j4 * 4 + 3];
    }
    btf[c * 384 + 128 + t] = f2bf(acc);
    if (t < 128) red[t] = bias1[t] * wcol[t];
    __syncthreads();
    for (int st = 64; st > 0; st >>= 1) {
      if (t < st) red[t] += red[t + st];
      __syncthreads();
    }
    if (t == 0) biasv[c] = red[0];
  }
}

// ---- xr GEMM: wave tile 64x64 (WM=4), block 128x128, 3-buf BK=32, counted vmcnt ----
template <int K, int WM>
__global__ __launch_bounds__(256, 3)
void k_mgemm(const unsigned short* __restrict__ A, const unsigned short* __restrict__ Bt,
             unsigned short* __restrict__ C, int M, int N, int gx) {
  constexpr int BM = WM * 32;
  constexpr int ACH = BM * 4;
  constexpr int TCH = ACH + 512;
  constexpr int LPT = TCH / 256;
  constexpr int NS = K / 32;
  constexpr int ABUF = BM * 32;
  constexpr int BBUF = 128 * 32;
  extern __shared__ unsigned short lds[];
  const int tid = threadIdx.x;
  const int lane = tid & 63;
  const int wave = tid >> 6;

  const int nwg = gridDim.x;
  const int q = nwg >> 3, r = nwg & 7;
  const int xcd = blockIdx.x & 7, bi = blockIdx.x >> 3;
  const int wg = (xcd < r ? xcd * (q + 1) : r * (q + 1) + (xcd - r) * q) + bi;
  const int bx = wg % gx;
  const int by = wg / gx;
  const int row0 = by * BM;
  const int colb = bx * 128;
  const int wcol = (wave & 1) * 64;
  const int wrow = (wave >> 1) * (WM * 16);
  const int lr = lane & 15;
  const int lko = lane >> 4;

  f32x4 acc[WM][4];
  #pragma unroll
  for (int i = 0; i < WM; i++)
    #pragma unroll
    for (int j = 0; j < 4; j++) acc[i][j] = (f32x4){0.f, 0.f, 0.f, 0.f};

  auto stage = [&](int k0, int b) {
    unsigned short* as = lds + b * ABUF;
    unsigned short* bs = lds + 3 * ABUF + b * BBUF;
    #pragma unroll
    for (int it = 0; it < LPT; it++) {
      int ci = it * 256 + tid;
      if (ci < ACH) {
        int row = ci >> 2, cs = ci & 3;
        int s = (row & 3) ^ ((row >> 2) & 3);
        int gm = row0 + row; if (gm >= M) gm = M - 1;
        gload_lds(A + (size_t)gm * K + k0 + ((cs ^ s) << 3), as + (size_t)ci * 8);
      } else {
        int cj = ci - ACH;
        int row = cj >> 2, cs = cj & 3;
        int s = (row & 3) ^ ((row >> 2) & 3);
        gload_lds(Bt + (size_t)(colb + row) * K + k0 + ((cs ^ s) << 3), bs + (size_t)cj * 8);
      }
    }
  };

  auto compute = [&](int b) {
    const unsigned short* as = lds + b * ABUF;
    const unsigned short* bs = lds + 3 * ABUF + b * BBUF;
    bf16x8 af[WM], bfr[4];
    #pragma unroll
    for (int mb = 0; mb < WM; mb++) {
      int rowL = wrow + mb * 16 + lr;
      int s = (rowL & 3) ^ ((rowL >> 2) & 3);
      af[mb] = *(const bf16x8*)&as[rowL * 32 + ((lko ^ s) << 3)];
    }
    #pragma unroll
    for (int nb = 0; nb < 4; nb++) {
      int colL = wcol + nb * 16 + lr;
      int s = (colL & 3) ^ ((colL >> 2) & 3);
      bfr[nb] = *(const bf16x8*)&bs[colL * 32 + ((lko ^ s) << 3)];
    }
    #pragma unroll
    for (int mb = 0; mb < WM; mb++)
      #pragma unroll
      for (int nb = 0; nb < 4; nb++)
        acc[mb][nb] = __builtin_amdgcn_mfma_f32_16x16x32_bf16(af[mb], bfr[nb], acc[mb][nb], 0, 0, 0);
  };

  stage(0, 0);
  stage(32, 1);
  wait_vmcnt<LPT>();
  __builtin_amdgcn_sched_barrier(0);
  __builtin_amdgcn_s_barrier();
  #pragma unroll
  for (int s = 0; s < NS; s++) {
    if (s + 2 < NS) stage((s + 2) * 32, (s + 2) % 3);
    compute(s % 3);
    if (s + 1 < NS) {
      if (s + 2 < NS) wait_vmcnt<LPT>();
      else            wait_vmcnt<0>();
      __builtin_amdgcn_sched_barrier(0);
      __builtin_amdgcn_s_barrier();
    }
  }

  __syncthreads();
  unsigned short* Cs = lds;                // [BM][128]
  const int orow = lko * 4;
  #pragma unroll
  for (int mb = 0; mb < WM; mb++) {
    #pragma unroll
    for (int i = 0; i < 4; i++) {
      int row = wrow + mb * 16 + orow + i;
      int sw = (row & 7) << 3;
      #pragma unroll
      for (int nb = 0; nb < 4; nb++) {
        int col = wcol + nb * 16 + lr;
        Cs[row * 128 + (col ^ sw)] = f2bf(acc[mb][nb][i]);
      }
    }
  }
  __syncthreads();
  #pragma unroll
  for (int it = 0; it < BM / 16; it++) {
    int off = it * 256 + tid;
    int row = off >> 4, jb = off & 15;
    int grow = row0 + row;
    if (grow < M) {
      int idx = row * 128 + ((jb * 8) ^ ((row & 7) << 3));
      u32x4 val = *(const u32x4*)&Cs[idx];
      __builtin_nontemporal_store(val, (u32x4*)&C[(size_t)grow * N + colb + jb * 8]);
    }
  }
}

// ---- fused GEMM: [xl|xrt] = [agg|nf] @ btf^T + biasv; split compact outputs ----
__global__ __launch_bounds__(256, 3)
void k_fused(const unsigned short* __restrict__ A1, const unsigned short* __restrict__ A2,
             const unsigned short* __restrict__ Bt, const float* __restrict__ biasv,
             unsigned short* __restrict__ xl, unsigned short* __restrict__ xrt, int M) {
  constexpr int K = 384, NS = 12, LPT = 4;
  extern __shared__ unsigned short lds[];
  const int tid = threadIdx.x;
  const int lane = tid & 63;
  const int wave = tid >> 6;

  const int nwg = gridDim.x;
  const int q = nwg >> 3, r = nwg & 7;
  const int xcd = blockIdx.x & 7, bi = blockIdx.x >> 3;
  const int wg = (xcd < r ? xcd * (q + 1) : r * (q + 1) + (xcd - r) * q) + bi;
  const int bx = wg & 1;
  const int by = wg >> 1;
  const int row0 = by * 128;
  const int colb = bx * 128;
  const int wcol = (wave & 1) * 64;
  const int wrow = (wave >> 1) * 64;
  const int lr = lane & 15;
  const int lko = lane >> 4;

  f32x4 acc[4][4];
  #pragma unroll
  for (int i = 0; i < 4; i++)
    #pragma unroll
    for (int j = 0; j < 4; j++) acc[i][j] = (f32x4){0.f, 0.f, 0.f, 0.f};

  auto stage = [&](int k0, int b) {
    unsigned short* as = lds + b * 4096;
    unsigned short* bs = lds + 3 * 4096 + b * 4096;
    #pragma unroll
    for (int it = 0; it < LPT; it++) {
      int ci = it * 256 + tid;
      if (ci < 512) {
        int row = ci >> 2, cs = ci & 3;
        int s = (row & 3) ^ ((row >> 2) & 3);
        int gm = row0 + row; if (gm >= M) gm = M - 1;
        const unsigned short* gp;
        if (k0 < 128) gp = A1 + (size_t)gm * 128 + k0 + ((cs ^ s) << 3);
        else          gp = A2 + (size_t)gm * 256 + (k0 - 128) + ((cs ^ s) << 3);
        gload_lds(gp, as + (size_t)ci * 8);
      } else {
        int cj = ci - 512;
        int row = cj >> 2, cs = cj & 3;
        int s = (row & 3) ^ ((row >> 2) & 3);
        gload_lds(Bt + (size_t)(colb + row) * K + k0 + ((cs ^ s) << 3), bs + (size_t)cj * 8);
      }
    }
  };

  auto compute = [&](int b) {
    const unsigned short* as = lds + b * 4096;
    const unsigned short* bs = lds + 3 * 4096 + b * 4096;
    bf16x8 af[4], bfr[4];
    #pragma unroll
    for (int mb = 0; mb < 4; mb++) {
      int rowL = wrow + mb * 16 + lr;
      int s = (rowL & 3) ^ ((rowL >> 2) & 3);
      af[mb] = *(const bf16x8*)&as[rowL * 32 + ((lko ^ s) << 3)];
    }
    #pragma unroll
    for (int nb = 0; nb < 4; nb++) {
      int colL = wcol + nb * 16 + lr;
      int s = (colL & 3) ^ ((colL >> 2) & 3);
      bfr[nb] = *(const bf16x8*)&bs[colL * 32 + ((lko ^ s) << 3)];
    }
    #pragma unroll
    for (int mb = 0; mb < 4; mb++)
      #pragma unroll
      for (int nb = 0; nb < 4; nb++)
        acc[mb][nb] = __builtin_amdgcn_mfma_f32_16x16x32_bf16(af[mb], bfr[nb], acc[mb][nb], 0, 0, 0);
  };

  stage(0, 0);
  stage(32, 1);
  wait_vmcnt<LPT>();
  __builtin_amdgcn_sched_barrier(0);
  __builtin_amdgcn_s_barrier();
  #pragma unroll
  for (int s = 0; s < NS; s++) {
    if (s + 2 < NS) stage((s + 2) * 32, (s + 2) % 3);
    compute(s % 3);
    if (s + 1 < NS) {
      if (s + 2 < NS) wait_vmcnt<LPT>();
      else            wait_vmcnt<0>();
      __builtin_amdgcn_sched_barrier(0);
      __builtin_amdgcn_s_barrier();
    }
  }

  __syncthreads();
  unsigned short* Cs = lds;                // [128][128]
  const int orow = lko * 4;
  #pragma unroll
  for (int mb = 0; mb < 4; mb++) {
    #pragma unroll
    for (int i = 0; i < 4; i++) {
      int row = wrow + mb * 16 + orow + i;
      int sw = (row & 7) << 3;
      #pragma unroll
      for (int nb = 0; nb < 4; nb++) {
        int col = wcol + nb * 16 + lr;
        Cs[row * 128 + (col ^ sw)] = f2bf(acc[mb][nb][i] + biasv[colb + col]);
      }
    }
  }
  __syncthreads();
  unsigned short* Cout = bx ? xrt : xl;    // compact [NN][128] each
  #pragma unroll
  for (int it = 0; it < 8; it++) {
    int off = it * 256 + tid;
    int row = off >> 4, jb = off & 15;
    int grow = row0 + row;
    if (grow < M) {
      int idx = row * 128 + ((jb * 8) ^ ((row & 7) << 3));
      *(u16x8*)&Cout[(size_t)grow * 128 + jb * 8] = *(const u16x8*)&Cs[idx];
    }
  }
}

// ---- per-(dst,rel) counts only ----
__global__ void k_deg(const int* __restrict__ ei, const int* __restrict__ et,
                      int* __restrict__ cnt2) {
  int e = blockIdx.x * 256 + threadIdx.x;
  if (e < NE) atomicAdd(&cnt2[ei[NE + e] * NREL + et[e]], 1);
}

__device__ __forceinline__ int node_deg(const int* cnt2, int n) {
  const int4* p = (const int4*)(cnt2 + n * NREL);
  int4 a = p[0], b = p[1];
  return a.x + a.y + a.z + a.w + b.x + b.y + b.z + b.w;
}

__global__ void k_scan_a(const int* __restrict__ cnt2, int* __restrict__ parts) {
  __shared__ int lds[256];
  int t = threadIdx.x;
  int base = blockIdx.x * 1024 + t * 4;
  int s = 0;
  #pragma unroll
  for (int j = 0; j < 4; j++) s += (base + j < NN) ? node_deg(cnt2, base + j) : 0;
  lds[t] = s;
  __syncthreads();
  for (int st = 128; st > 0; st >>= 1) {
    if (t < st) lds[t] += lds[t + st];
    __syncthreads();
  }
  if (t == 0) parts[blockIdx.x] = lds[0];
}

// scan_c with inline partial-scan (scan_b folded in; parts = raw chunk sums)
__global__ void k_scan_c(const int* __restrict__ cnt2, const int* __restrict__ parts,
                         int* __restrict__ rowptr) {
  __shared__ int lds[256];
  __shared__ int blkoff;
  int t = threadIdx.x;
  // wave 0: exclusive-scan the 49 chunk partials, pick my block's offset
  if (t < 64) {
    int v = (t < NCHUNKS) ? parts[t] : 0;
    int x = v;
    #pragma unroll
    for (int off = 1; off < 64; off <<= 1) {
      int y = __shfl_up(x, off, 64);
      if (t >= off) x += y;
    }
    if (t == (int)blockIdx.x) blkoff = x - v;
  }
  int base = blockIdx.x * 1024 + t * 4;
  int v[4];
  int s = 0;
  #pragma unroll
  for (int j = 0; j < 4; j++) { v[j] = (base + j < NN) ? node_deg(cnt2, base + j) : 0; s += v[j]; }
  lds[t] = s;
  __syncthreads();
  for (int st = 1; st < 256; st <<= 1) {
    int add = (t >= st) ? lds[t - st] : 0;
    __syncthreads();
    lds[t] += add;
    __syncthreads();
  }
  int excl = lds[t] - s;
  int off = blkoff;
  int run = 0;
  #pragma unroll
  for (int j = 0; j < 4; j++) {
    run += v[j];
    if (base + j < NN) rowptr[base + j + 1] = off + excl + run;
  }
  if (blockIdx.x == 0 && t == 0) rowptr[0] = 0;
}

// pack (src:16 | rel:3@16 | cnt:13@19) — wgt array eliminated
__global__ void k_scatter(const int* __restrict__ ei, const int* __restrict__ et,
                          const int* __restrict__ rowptr, const int* __restrict__ cnt2,
                          int* __restrict__ cursor, unsigned int* __restrict__ csr) {
  int e = blockIdx.x * 256 + threadIdx.x;
  if (e < NE) {
    int d = ei[NE + e];
    int r = et[e];
    int pos = atomicAdd(&cursor[d], 1);
    unsigned int cnt = (unsigned int)cnt2[d * NREL + r];
    csr[rowptr[d] + pos] = (unsigned int)ei[e] | ((unsigned int)r << 16) | (cnt << 19);
  }
}

// ---- RGCN aggregation: half-wave per dst, masked batch-8, cnt-packed csr ----
__global__ __launch_bounds__(256)
void k_rgcn(const unsigned short* __restrict__ xr, const unsigned int* __restrict__ csr2,
            const int* __restrict__ rowptr, unsigned short* __restrict__ agg) {
  int wpair = (blockIdx.x * 256 + threadIdx.x) >> 6;
  int lane = threadIdx.x & 63;
  int hb = lane & 32;
  int l = lane & 31;
  int wid = wpair * 2 + (hb >> 5);
  if (wid >= NN) return;
  int c0 = l * 4;
  float a0 = 0.f, a1 = 0.f, a2 = 0.f, a3 = 0.f;
  int beg = rowptr[wid], end = rowptr[wid + 1];
  for (int j0 = beg; j0 < end; j0 += 32) {
    int nv = end - j0; if (nv > 32) nv = 32;
    unsigned int pk = (l < nv) ? csr2[j0 + l] : 0u;
    for (int t = 0; t < nv; t += 8) {
      uint2 wv[8]; float wz[8];
      #pragma unroll
      for (int z = 0; z < 8; z++) {
        unsigned int p = (unsigned int)__shfl((int)pk, hb + t + z, 64);
        if (t + z < nv) {
          size_t off = (size_t)(p & 0xFFFF) * XRLD + ((p >> 16) & 7) * H1 + c0;
          wv[z] = *(const uint2*)(xr + off);
          wz[z] = __builtin_amdgcn_rcpf((float)(p >> 19));
        } else {
          wv[z] = make_uint2(0, 0);
          wz[z] = 0.f;
        }
      }
      #pragma unroll
      for (int z = 0; z < 8; z++) {
        a0 += wz[z] * bf2f((unsigned short)(wv[z].x & 0xffff));
        a1 += wz[z] * bf2f((unsigned short)(wv[z].x >> 16));
        a2 += wz[z] * bf2f((unsigned short)(wv[z].y & 0xffff));
        a3 += wz[z] * bf2f((unsigned short)(wv[z].y >> 16));
      }
    }
  }
  uint2 packed;
  packed.x = (uint32_t)f2bf(a0) | ((uint32_t)f2bf(a1) << 16);
  packed.y = (uint32_t)f2bf(a2) | ((uint32_t)f2bf(a3) << 16);
  *(uint2*)&agg[(size_t)wid * H1 + c0] = packed;
}

// ---- GATv2: half-wave per dst, compact xl gathers, masked batch-8 ----
__global__ __launch_bounds__(256)
void k_gat(const unsigned short* __restrict__ xl, const unsigned short* __restrict__ xrt,
           const unsigned int* __restrict__ csr2, const int* __restrict__ rowptr,
           const float* __restrict__ att, const float* __restrict__ bias2,
           float* __restrict__ out) {
  int wpair = (blockIdx.x * 256 + threadIdx.x) >> 6;
  int lane = threadIdx.x & 63;
  int hb = lane & 32;
  int l = lane & 31;
  int wid = wpair * 2 + (hb >> 5);
  if (wid >= NN) return;
  int c0 = l * 4;
  float4 at = *(const float4*)(att + c0);
  uint2 wr2 = *(const uint2*)(xrt + (size_t)wid * 128 + c0);
  float xr0 = bf2f((unsigned short)(wr2.x & 0xffff));
  float xr1 = bf2f((unsigned short)(wr2.x >> 16));
  float xr2 = bf2f((unsigned short)(wr2.y & 0xffff));
  float xr3 = bf2f((unsigned short)(wr2.y >> 16));
  uint2 wv0 = *(const uint2*)(xl + (size_t)wid * 128 + c0);
  float v0 = bf2f((unsigned short)(wv0.x & 0xffff));
  float v1 = bf2f((unsigned short)(wv0.x >> 16));
  float v2 = bf2f((unsigned short)(wv0.y & 0xffff));
  float v3 = bf2f((unsigned short)(wv0.y >> 16));
  float ep = lrelu(v0 + xr0) * at.x + lrelu(v1 + xr1) * at.y +
             lrelu(v2 + xr2) * at.z + lrelu(v3 + xr3) * at.w;
  #pragma unroll
  for (int off = 16; off > 0; off >>= 1) ep += __shfl_xor(ep, off, 64);
  float m = ep, s = 1.f, o0 = v0, o1 = v1, o2 = v2, o3 = v3;
  int beg = rowptr[wid], end = rowptr[wid + 1];
  for (int j0 = beg; j0 < end; j0 += 32) {
    int nv = end - j0; if (nv > 32) nv = 32;
    unsigned int pk = (l < nv) ? csr2[j0 + l] : 0u;
    for (int t = 0; t < nv; t += 8) {
      float u0[8], u1[8], u2[8], u3[8], p[8];
      #pragma unroll
      for (int z = 0; z < 8; z++) {
        unsigned int pv = (unsigned int)__shfl((int)pk, hb + t + z, 64);
        int src = (int)(pv & 0xFFFF);
        uint2 wu;
        if (t + z < nv) wu = *(const uint2*)(xl + (size_t)src * 128 + c0);
        else            wu = make_uint2(0, 0);
        u0[z] = bf2f((unsigned short)(wu.x & 0xffff));
        u1[z] = bf2f((unsigned short)(wu.x >> 16));
        u2[z] = bf2f((unsigned short)(wu.y & 0xffff));
        u3[z] = bf2f((unsigned short)(wu.y >> 16));
      }
      #pragma unroll
      for (int z = 0; z < 8; z++)
        p[z] = lrelu(u0[z] + xr0) * at.x + lrelu(u1[z] + xr1) * at.y +
               lrelu(u2[z] + xr2) * at.z + lrelu(u3[z] + xr3) * at.w;
      #pragma unroll
      for (int off = 16; off > 0; off >>= 1) {
        #pragma unroll
        for (int z = 0; z < 8; z++) p[z] += __shfl_xor(p[z], off, 64);
      }
      #pragma unroll
      for (int z = 0; z < 8; z++) if (t + z >= nv) p[z] = -1e30f;
      float pm = p[0];
      #pragma unroll
      for (int z = 1; z < 8; z++) pm = fmaxf(pm, p[z]);
      float mn = fmaxf(m, pm);
      float sc = __expf(m - mn);
      float e[8];
      #pragma unroll
      for (int z = 0; z < 8; z++) e[z] = __expf(p[z] - mn);
      float es = 0.f, e0 = 0.f, e1 = 0.f, e2 = 0.f, e3 = 0.f;
      #pragma unroll
      for (int z = 0; z < 8; z++) {
        es += e[z]; e0 += e[z] * u0[z]; e1 += e[z] * u1[z];
        e2 += e[z] * u2[z]; e3 += e[z] * u3[z];
      }
      s = s * sc + es;
      o0 = o0 * sc + e0; o1 = o1 * sc + e1;
      o2 = o2 * sc + e2; o3 = o3 * sc + e3;
      m = mn;
    }
  }
  float inv = 1.f / s;
  float4 b2 = *(const float4*)(bias2 + c0);
  float4 res = make_float4(o0 * inv + b2.x, o1 * inv + b2.y,
                           o2 * inv + b2.z, o3 * inv + b2.w);
  *(float4*)&out[(size_t)wid * H1 + c0] = res;
}

extern "C" void kernel_launch(void* const* d_in, const int* in_sizes, int n_in,
                              void* d_out, int out_size, void* d_ws, size_t ws_size,
                              hipStream_t stream) {
  const float* nf    = (const float*)d_in[0];
  const int*   ei    = (const int*)d_in[1];
  const int*   et    = (const int*)d_in[3];
  const float* basis = (const float*)d_in[4];
  const float* comp  = (const float*)d_in[5];
  const float* root  = (const float*)d_in[6];
  const float* bias1 = (const float*)d_in[7];
  const float* w_l   = (const float*)d_in[8];
  const float* w_r   = (const float*)d_in[9];
  const float* att   = (const float*)d_in[10];
  const float* bias2 = (const float*)d_in[11];
  float* out = (float*)d_out;

  char* ws = (char*)d_ws;
  unsigned short* xr_bf  = (unsigned short*)ws;                    // [NN][1024] 102.4 MB
  unsigned short* nf_bf  = (unsigned short*)(ws + 102400000);      // [NN][256]  25.6 MB
  unsigned short* wrb_t  = (unsigned short*)(ws + 128000000);      // [1024][256]
  unsigned short* btf    = (unsigned short*)(ws + 128524288);      // [256][384] bf16
  float*          biasv  = (float*)(ws + 128720896);               // [256]
  unsigned short* agg_bf = (unsigned short*)(ws + 128721920);      // [NN][128] bf16
  int*            cursor = (int*)(ws + 141521920);                 // [NN]
  int*            cnt2   = cursor + NN;                            // [NN*8]
  int*            rowptr = cnt2 + NN * NREL;                       // [NN+1]
  unsigned int*   csr    = (unsigned int*)(rowptr + NN + 1);       // [NE]
  int*            parts  = (int*)(csr + NE);                       // [64]
  // overlays into xr region (dead after k_rgcn): compact split outputs
  unsigned short* xl_bf  = (unsigned short*)ws;                    // [NN][128] 12.8 MB
  unsigned short* xrt_bf = (unsigned short*)(ws + 12800000);       // [NN][128] 12.8 MB

  hipMemsetAsync(cursor, 0, (1 + NREL) * NN * sizeof(int), stream);

  k_pre3<<<PRE_ALL_BLKS, 256, 0, stream>>>(nf, nf_bf, basis, comp, wrb_t,
                                           root, w_l, w_r, bias1, btf, biasv);

  const int GY128 = (NN + 127) / 128;   // 391
  k_mgemm<256, 4><<<8 * GY128, 256, 49152, stream>>>(
      nf_bf, wrb_t, xr_bf, NN, XRLD, 8);

  k_deg<<<(NE + 255) / 256, 256, 0, stream>>>(ei, et, cnt2);
  k_scan_a<<<NCHUNKS, 256, 0, stream>>>(cnt2, parts);
  k_scan_c<<<NCHUNKS, 256, 0, stream>>>(cnt2, parts, rowptr);
  k_scatter<<<(NE + 255) / 256, 256, 0, stream>>>(ei, et, rowptr, cnt2, cursor, csr);

  k_rgcn<<<(NN + 7) / 8, 256, 0, stream>>>(xr_bf, csr, rowptr, agg_bf);

  k_fused<<<2 * GY128, 256, 49152, stream>>>(agg_bf, nf_bf, btf, biasv, xl_bf, xrt_bf, NN);

  k_gat<<<(NN + 7) / 8, 256, 0, stream>>>(xl_bf, xrt_bf, csr, rowptr, att, bias2, out);
}

// Round 19
// 212.968 us; speedup vs baseline: 1.2013x; 1.1295x over previous
//
#include <hip/hip_runtime.h>
#include <hip/hip_bf16.h>
#include <cstdint>
#include <cstddef>

#define NN 50000
#define NE 500000
#define GD 256
#define H1 128
#define H2 128
#define NREL 8
#define NBASES 30
#define XRLD (NREL * H1)   // 1024
#define NCHUNKS ((NN + 1023) / 1024)  // 49

typedef __attribute__((ext_vector_type(8))) short bf16x8;
typedef __attribute__((ext_vector_type(4))) float f32x4;
typedef __attribute__((ext_vector_type(8))) unsigned short u16x8;
typedef __attribute__((ext_vector_type(4))) unsigned int u32x4;

__device__ __forceinline__ float lrelu(float x) { return x > 0.f ? x : 0.2f * x; }

// manual RTNE (no NaN path) — proven fastest (R13 vs R14 A/B)
__device__ __forceinline__ unsigned short f2bf(float x) {
  union { float f; uint32_t u; } v; v.f = x;
  uint32_t r = v.u + 0x7FFF + ((v.u >> 16) & 1);
  return (unsigned short)(r >> 16);
}
__device__ __forceinline__ float bf2f(unsigned short u) {
  union { uint32_t u; float f; } v; v.u = ((uint32_t)u) << 16;
  return v.f;
}

template <int N>
__device__ __forceinline__ void wait_vmcnt() {
  asm volatile("s_waitcnt vmcnt(%0)" :: "n"(N) : "memory");
}

__device__ __forceinline__ void gload_lds(const unsigned short* gp, unsigned short* lp) {
  __builtin_amdgcn_global_load_lds(
      (const __attribute__((address_space(1))) void*)gp,
      (__attribute__((address_space(3))) void*)lp, 16, 0, 0);
}

// ---- merged prep, bandwidth-tuned ----
// cast: 32 floats/thread (8 independent float4 loads in flight)
// wr:   block=k, lanes=o (coalesced basis reads), 4 r-outputs per thread
#define PRE_CAST_BLKS 1563                       // ceil(NN*GD/32 / 256)
#define PRE_WR_BLKS   256                        // one per k
#define PRE_ALL_BLKS  (PRE_CAST_BLKS + PRE_WR_BLKS + 256)
__global__ __launch_bounds__(256)
void k_pre3(const float* __restrict__ nf, unsigned short* __restrict__ nf_bf,
            const float* __restrict__ basis, const float* __restrict__ comp,
            unsigned short* __restrict__ wrb_t,
            const float* __restrict__ root, const float* __restrict__ w_l,
            const float* __restrict__ w_r, const float* __restrict__ bias1,
            unsigned short* __restrict__ btf, float* __restrict__ biasv) {
  __shared__ float wcol[128];
  __shared__ float red[128];
  const int b = blockIdx.x;
  const int t = threadIdx.x;
  if (b < PRE_CAST_BLKS) {
    // fp32 -> bf16 cast, 32 elems/thread, deep ILP
    int i = b * 256 + t;                  // chunk id, 32 floats each
    if (i < NN * GD / 32) {
      const float4* p = (const float4*)(nf + (size_t)i * 32);
      float4 v[8];
      #pragma unroll
      for (int j = 0; j < 8; j++) v[j] = p[j];     // 8 loads issued together
      #pragma unroll
      for (int j = 0; j < 4; j++) {
        u16x8 r;
        r[0] = f2bf(v[2 * j].x); r[1] = f2bf(v[2 * j].y);
        r[2] = f2bf(v[2 * j].z); r[3] = f2bf(v[2 * j].w);
        r[4] = f2bf(v[2 * j + 1].x); r[5] = f2bf(v[2 * j + 1].y);
        r[6] = f2bf(v[2 * j + 1].z); r[7] = f2bf(v[2 * j + 1].w);
        *(u16x8*)(nf_bf + (size_t)i * 32 + j * 8) = r;
      }
    }
  } else if (b < PRE_CAST_BLKS + PRE_WR_BLKS) {
    // wrb_t[(r*128+o)*256+k] = sum_bs comp[r][bs]*basis[bs][k][o]
    int k = b - PRE_CAST_BLKS;            // 0..255
    int o = t & 127;
    int rbase = t >> 7;                   // 0 or 1
    float acc[4] = {0.f, 0.f, 0.f, 0.f};
    #pragma unroll
    for (int bs = 0; bs < NBASES; bs++) {
      float bval = basis[((size_t)bs * GD + k) * H1 + o];   // lane-coalesced in o
      #pragma unroll
      for (int rr = 0; rr < 4; rr++)
        acc[rr] += comp[(rbase + 2 * rr) * NBASES + bs] * bval;
    }
    #pragma unroll
    for (int rr = 0; rr < 4; rr++) {
      int r = rbase + 2 * rr;
      wrb_t[(((r << 7) + o) << 8) + k] = f2bf(acc[rr]);
    }
  } else {
    // prep2: one block per output column c
    int c = b - (PRE_CAST_BLKS + PRE_WR_BLKS);   // 0..255
    if (t < 128) {
      float v = (c < H2) ? w_l[t * H2 + c] : w_r[t * H2 + (c - H2)];
      wcol[t] = v;
      btf[c * 384 + t] = f2bf(v);
    }
    __syncthreads();
    const float4* rp = (const float4*)(root + (size_t)t * H1);
    float acc = 0.f;
    #pragma unroll
    for (int j4 = 0; j4 < 32; j4++) {
      float4 r4 = rp[j4];
      acc += r4.x * wcol[j4 * 4 + 0] + r4.y * wcol[j4 * 4 + 1] +
             r4.z * wcol[j4 * 4 + 2] + r4.w * wcol[j4 * 4 + 3];
    }
    btf[c * 384 + 128 + t] = f2bf(acc);
    if (t < 128) red[t] = bias1[t] * wcol[t];
    __syncthreads();
    for (int st = 64; st > 0; st >>= 1) {
      if (t < st) red[t] += red[t + st];
      __syncthreads();
    }
    if (t == 0) biasv[c] = red[0];
  }
}

// ---- xr GEMM: wave tile 64x64 (WM=4), block 128x128, 3-buf BK=32, counted vmcnt ----
template <int K, int WM>
__global__ __launch_bounds__(256, 3)
void k_mgemm(const unsigned short* __restrict__ A, const unsigned short* __restrict__ Bt,
             unsigned short* __restrict__ C, int M, int N, int gx) {
  constexpr int BM = WM * 32;
  constexpr int ACH = BM * 4;
  constexpr int TCH = ACH + 512;
  constexpr int LPT = TCH / 256;
  constexpr int NS = K / 32;
  constexpr int ABUF = BM * 32;
  constexpr int BBUF = 128 * 32;
  extern __shared__ unsigned short lds[];
  const int tid = threadIdx.x;
  const int lane = tid & 63;
  const int wave = tid >> 6;

  const int nwg = gridDim.x;
  const int q = nwg >> 3, r = nwg & 7;
  const int xcd = blockIdx.x & 7, bi = blockIdx.x >> 3;
  const int wg = (xcd < r ? xcd * (q + 1) : r * (q + 1) + (xcd - r) * q) + bi;
  const int bx = wg % gx;
  const int by = wg / gx;
  const int row0 = by * BM;
  const int colb = bx * 128;
  const int wcol = (wave & 1) * 64;
  const int wrow = (wave >> 1) * (WM * 16);
  const int lr = lane & 15;
  const int lko = lane >> 4;

  f32x4 acc[WM][4];
  #pragma unroll
  for (int i = 0; i < WM; i++)
    #pragma unroll
    for (int j = 0; j < 4; j++) acc[i][j] = (f32x4){0.f, 0.f, 0.f, 0.f};

  auto stage = [&](int k0, int b) {
    unsigned short* as = lds + b * ABUF;
    unsigned short* bs = lds + 3 * ABUF + b * BBUF;
    #pragma unroll
    for (int it = 0; it < LPT; it++) {
      int ci = it * 256 + tid;
      if (ci < ACH) {
        int row = ci >> 2, cs = ci & 3;
        int s = (row & 3) ^ ((row >> 2) & 3);
        int gm = row0 + row; if (gm >= M) gm = M - 1;
        gload_lds(A + (size_t)gm * K + k0 + ((cs ^ s) << 3), as + (size_t)ci * 8);
      } else {
        int cj = ci - ACH;
        int row = cj >> 2, cs = cj & 3;
        int s = (row & 3) ^ ((row >> 2) & 3);
        gload_lds(Bt + (size_t)(colb + row) * K + k0 + ((cs ^ s) << 3), bs + (size_t)cj * 8);
      }
    }
  };

  auto compute = [&](int b) {
    const unsigned short* as = lds + b * ABUF;
    const unsigned short* bs = lds + 3 * ABUF + b * BBUF;
    bf16x8 af[WM], bfr[4];
    #pragma unroll
    for (int mb = 0; mb < WM; mb++) {
      int rowL = wrow + mb * 16 + lr;
      int s = (rowL & 3) ^ ((rowL >> 2) & 3);
      af[mb] = *(const bf16x8*)&as[rowL * 32 + ((lko ^ s) << 3)];
    }
    #pragma unroll
    for (int nb = 0; nb < 4; nb++) {
      int colL = wcol + nb * 16 + lr;
      int s = (colL & 3) ^ ((colL >> 2) & 3);
      bfr[nb] = *(const bf16x8*)&bs[colL * 32 + ((lko ^ s) << 3)];
    }
    #pragma unroll
    for (int mb = 0; mb < WM; mb++)
      #pragma unroll
      for (int nb = 0; nb < 4; nb++)
        acc[mb][nb] = __builtin_amdgcn_mfma_f32_16x16x32_bf16(af[mb], bfr[nb], acc[mb][nb], 0, 0, 0);
  };

  stage(0, 0);
  stage(32, 1);
  wait_vmcnt<LPT>();
  __builtin_amdgcn_sched_barrier(0);
  __builtin_amdgcn_s_barrier();
  #pragma unroll
  for (int s = 0; s < NS; s++) {
    if (s + 2 < NS) stage((s + 2) * 32, (s + 2) % 3);
    compute(s % 3);
    if (s + 1 < NS) {
      if (s + 2 < NS) wait_vmcnt<LPT>();
      else            wait_vmcnt<0>();
      __builtin_amdgcn_sched_barrier(0);
      __builtin_amdgcn_s_barrier();
    }
  }

  __syncthreads();
  unsigned short* Cs = lds;                // [BM][128]
  const int orow = lko * 4;
  #pragma unroll
  for (int mb = 0; mb < WM; mb++) {
    #pragma unroll
    for (int i = 0; i < 4; i++) {
      int row = wrow + mb * 16 + orow + i;
      int sw = (row & 7) << 3;
      #pragma unroll
      for (int nb = 0; nb < 4; nb++) {
        int col = wcol + nb * 16 + lr;
        Cs[row * 128 + (col ^ sw)] = f2bf(acc[mb][nb][i]);
      }
    }
  }
  __syncthreads();
  #pragma unroll
  for (int it = 0; it < BM / 16; it++) {
    int off = it * 256 + tid;
    int row = off >> 4, jb = off & 15;
    int grow = row0 + row;
    if (grow < M) {
      int idx = row * 128 + ((jb * 8) ^ ((row & 7) << 3));
      u32x4 val = *(const u32x4*)&Cs[idx];
      __builtin_nontemporal_store(val, (u32x4*)&C[(size_t)grow * N + colb + jb * 8]);
    }
  }
}

// ---- fused GEMM: [xl|xrt] = [agg|nf] @ btf^T + biasv; split compact outputs ----
__global__ __launch_bounds__(256, 3)
void k_fused(const unsigned short* __restrict__ A1, const unsigned short* __restrict__ A2,
             const unsigned short* __restrict__ Bt, const float* __restrict__ biasv,
             unsigned short* __restrict__ xl, unsigned short* __restrict__ xrt, int M) {
  constexpr int K = 384, NS = 12, LPT = 4;
  extern __shared__ unsigned short lds[];
  const int tid = threadIdx.x;
  const int lane = tid & 63;
  const int wave = tid >> 6;

  const int nwg = gridDim.x;
  const int q = nwg >> 3, r = nwg & 7;
  const int xcd = blockIdx.x & 7, bi = blockIdx.x >> 3;
  const int wg = (xcd < r ? xcd * (q + 1) : r * (q + 1) + (xcd - r) * q) + bi;
  const int bx = wg & 1;
  const int by = wg >> 1;
  const int row0 = by * 128;
  const int colb = bx * 128;
  const int wcol = (wave & 1) * 64;
  const int wrow = (wave >> 1) * 64;
  const int lr = lane & 15;
  const int lko = lane >> 4;

  f32x4 acc[4][4];
  #pragma unroll
  for (int i = 0; i < 4; i++)
    #pragma unroll
    for (int j = 0; j < 4; j++) acc[i][j] = (f32x4){0.f, 0.f, 0.f, 0.f};

  auto stage = [&](int k0, int b) {
    unsigned short* as = lds + b * 4096;
    unsigned short* bs = lds + 3 * 4096 + b * 4096;
    #pragma unroll
    for (int it = 0; it < LPT; it++) {
      int ci = it * 256 + tid;
      if (ci < 512) {
        int row = ci >> 2, cs = ci & 3;
        int s = (row & 3) ^ ((row >> 2) & 3);
        int gm = row0 + row; if (gm >= M) gm = M - 1;
        const unsigned short* gp;
        if (k0 < 128) gp = A1 + (size_t)gm * 128 + k0 + ((cs ^ s) << 3);
        else          gp = A2 + (size_t)gm * 256 + (k0 - 128) + ((cs ^ s) << 3);
        gload_lds(gp, as + (size_t)ci * 8);
      } else {
        int cj = ci - 512;
        int row = cj >> 2, cs = cj & 3;
        int s = (row & 3) ^ ((row >> 2) & 3);
        gload_lds(Bt + (size_t)(colb + row) * K + k0 + ((cs ^ s) << 3), bs + (size_t)cj * 8);
      }
    }
  };

  auto compute = [&](int b) {
    const unsigned short* as = lds + b * 4096;
    const unsigned short* bs = lds + 3 * 4096 + b * 4096;
    bf16x8 af[4], bfr[4];
    #pragma unroll
    for (int mb = 0; mb < 4; mb++) {
      int rowL = wrow + mb * 16 + lr;
      int s = (rowL & 3) ^ ((rowL >> 2) & 3);
      af[mb] = *(const bf16x8*)&as[rowL * 32 + ((lko ^ s) << 3)];
    }
    #pragma unroll
    for (int nb = 0; nb < 4; nb++) {
      int colL = wcol + nb * 16 + lr;
      int s = (colL & 3) ^ ((colL >> 2) & 3);
      bfr[nb] = *(const bf16x8*)&bs[colL * 32 + ((lko ^ s) << 3)];
    }
    #pragma unroll
    for (int mb = 0; mb < 4; mb++)
      #pragma unroll
      for (int nb = 0; nb < 4; nb++)
        acc[mb][nb] = __builtin_amdgcn_mfma_f32_16x16x32_bf16(af[mb], bfr[nb], acc[mb][nb], 0, 0, 0);
  };

  stage(0, 0);
  stage(32, 1);
  wait_vmcnt<LPT>();
  __builtin_amdgcn_sched_barrier(0);
  __builtin_amdgcn_s_barrier();
  #pragma unroll
  for (int s = 0; s < NS; s++) {
    if (s + 2 < NS) stage((s + 2) * 32, (s + 2) % 3);
    compute(s % 3);
    if (s + 1 < NS) {
      if (s + 2 < NS) wait_vmcnt<LPT>();
      else            wait_vmcnt<0>();
      __builtin_amdgcn_sched_barrier(0);
      __builtin_amdgcn_s_barrier();
    }
  }

  __syncthreads();
  unsigned short* Cs = lds;                // [128][128]
  const int orow = lko * 4;
  #pragma unroll
  for (int mb = 0; mb < 4; mb++) {
    #pragma unroll
    for (int i = 0; i < 4; i++) {
      int row = wrow + mb * 16 + orow + i;
      int sw = (row & 7) << 3;
      #pragma unroll
      for (int nb = 0; nb < 4; nb++) {
        int col = wcol + nb * 16 + lr;
        Cs[row * 128 + (col ^ sw)] = f2bf(acc[mb][nb][i] + biasv[colb + col]);
      }
    }
  }
  __syncthreads();
  unsigned short* Cout = bx ? xrt : xl;    // compact [NN][128] each
  #pragma unroll
  for (int it = 0; it < 8; it++) {
    int off = it * 256 + tid;
    int row = off >> 4, jb = off & 15;
    int grow = row0 + row;
    if (grow < M) {
      int idx = row * 128 + ((jb * 8) ^ ((row & 7) << 3));
      *(u16x8*)&Cout[(size_t)grow * 128 + jb * 8] = *(const u16x8*)&Cs[idx];
    }
  }
}

// ---- per-(dst,rel) counts only ----
__global__ void k_deg(const int* __restrict__ ei, const int* __restrict__ et,
                      int* __restrict__ cnt2) {
  int e = blockIdx.x * 256 + threadIdx.x;
  if (e < NE) atomicAdd(&cnt2[ei[NE + e] * NREL + et[e]], 1);
}

__device__ __forceinline__ int node_deg(const int* cnt2, int n) {
  const int4* p = (const int4*)(cnt2 + n * NREL);
  int4 a = p[0], b = p[1];
  return a.x + a.y + a.z + a.w + b.x + b.y + b.z + b.w;
}

__global__ void k_scan_a(const int* __restrict__ cnt2, int* __restrict__ parts) {
  __shared__ int lds[256];
  int t = threadIdx.x;
  int base = blockIdx.x * 1024 + t * 4;
  int s = 0;
  #pragma unroll
  for (int j = 0; j < 4; j++) s += (base + j < NN) ? node_deg(cnt2, base + j) : 0;
  lds[t] = s;
  __syncthreads();
  for (int st = 128; st > 0; st >>= 1) {
    if (t < st) lds[t] += lds[t + st];
    __syncthreads();
  }
  if (t == 0) parts[blockIdx.x] = lds[0];
}

// scan_c with inline partial-scan (scan_b folded in; parts = raw chunk sums)
__global__ void k_scan_c(const int* __restrict__ cnt2, const int* __restrict__ parts,
                         int* __restrict__ rowptr) {
  __shared__ int lds[256];
  __shared__ int blkoff;
  int t = threadIdx.x;
  if (t < 64) {
    int v = (t < NCHUNKS) ? parts[t] : 0;
    int x = v;
    #pragma unroll
    for (int off = 1; off < 64; off <<= 1) {
      int y = __shfl_up(x, off, 64);
      if (t >= off) x += y;
    }
    if (t == (int)blockIdx.x) blkoff = x - v;
  }
  int base = blockIdx.x * 1024 + t * 4;
  int v[4];
  int s = 0;
  #pragma unroll
  for (int j = 0; j < 4; j++) { v[j] = (base + j < NN) ? node_deg(cnt2, base + j) : 0; s += v[j]; }
  lds[t] = s;
  __syncthreads();
  for (int st = 1; st < 256; st <<= 1) {
    int add = (t >= st) ? lds[t - st] : 0;
    __syncthreads();
    lds[t] += add;
    __syncthreads();
  }
  int excl = lds[t] - s;
  int off = blkoff;
  int run = 0;
  #pragma unroll
  for (int j = 0; j < 4; j++) {
    run += v[j];
    if (base + j < NN) rowptr[base + j + 1] = off + excl + run;
  }
  if (blockIdx.x == 0 && t == 0) rowptr[0] = 0;
}

// pack (src:16 | rel:3@16 | cnt:13@19)
__global__ void k_scatter(const int* __restrict__ ei, const int* __restrict__ et,
                          const int* __restrict__ rowptr, const int* __restrict__ cnt2,
                          int* __restrict__ cursor, unsigned int* __restrict__ csr) {
  int e = blockIdx.x * 256 + threadIdx.x;
  if (e < NE) {
    int d = ei[NE + e];
    int r = et[e];
    int pos = atomicAdd(&cursor[d], 1);
    unsigned int cnt = (unsigned int)cnt2[d * NREL + r];
    csr[rowptr[d] + pos] = (unsigned int)ei[e] | ((unsigned int)r << 16) | (cnt << 19);
  }
}

// ---- RGCN aggregation: half-wave per dst, masked batch-8, cnt-packed csr ----
__global__ __launch_bounds__(256)
void k_rgcn(const unsigned short* __restrict__ xr, const unsigned int* __restrict__ csr2,
            const int* __restrict__ rowptr, unsigned short* __restrict__ agg) {
  int wpair = (blockIdx.x * 256 + threadIdx.x) >> 6;
  int lane = threadIdx.x & 63;
  int hb = lane & 32;
  int l = lane & 31;
  int wid = wpair * 2 + (hb >> 5);
  if (wid >= NN) return;
  int c0 = l * 4;
  float a0 = 0.f, a1 = 0.f, a2 = 0.f, a3 = 0.f;
  int beg = rowptr[wid], end = rowptr[wid + 1];
  for (int j0 = beg; j0 < end; j0 += 32) {
    int nv = end - j0; if (nv > 32) nv = 32;
    unsigned int pk = (l < nv) ? csr2[j0 + l] : 0u;
    for (int t = 0; t < nv; t += 8) {
      uint2 wv[8]; float wz[8];
      #pragma unroll
      for (int z = 0; z < 8; z++) {
        unsigned int p = (unsigned int)__shfl((int)pk, hb + t + z, 64);
        if (t + z < nv) {
          size_t off = (size_t)(p & 0xFFFF) * XRLD + ((p >> 16) & 7) * H1 + c0;
          wv[z] = *(const uint2*)(xr + off);
          wz[z] = __builtin_amdgcn_rcpf((float)(p >> 19));
        } else {
          wv[z] = make_uint2(0, 0);
          wz[z] = 0.f;
        }
      }
      #pragma unroll
      for (int z = 0; z < 8; z++) {
        a0 += wz[z] * bf2f((unsigned short)(wv[z].x & 0xffff));
        a1 += wz[z] * bf2f((unsigned short)(wv[z].x >> 16));
        a2 += wz[z] * bf2f((unsigned short)(wv[z].y & 0xffff));
        a3 += wz[z] * bf2f((unsigned short)(wv[z].y >> 16));
      }
    }
  }
  uint2 packed;
  packed.x = (uint32_t)f2bf(a0) | ((uint32_t)f2bf(a1) << 16);
  packed.y = (uint32_t)f2bf(a2) | ((uint32_t)f2bf(a3) << 16);
  *(uint2*)&agg[(size_t)wid * H1 + c0] = packed;
}

// ---- GATv2: half-wave per dst, compact xl gathers, masked batch-8 ----
__global__ __launch_bounds__(256)
void k_gat(const unsigned short* __restrict__ xl, const unsigned short* __restrict__ xrt,
           const unsigned int* __restrict__ csr2, const int* __restrict__ rowptr,
           const float* __restrict__ att, const float* __restrict__ bias2,
           float* __restrict__ out) {
  int wpair = (blockIdx.x * 256 + threadIdx.x) >> 6;
  int lane = threadIdx.x & 63;
  int hb = lane & 32;
  int l = lane & 31;
  int wid = wpair * 2 + (hb >> 5);
  if (wid >= NN) return;
  int c0 = l * 4;
  float4 at = *(const float4*)(att + c0);
  uint2 wr2 = *(const uint2*)(xrt + (size_t)wid * 128 + c0);
  float xr0 = bf2f((unsigned short)(wr2.x & 0xffff));
  float xr1 = bf2f((unsigned short)(wr2.x >> 16));
  float xr2 = bf2f((unsigned short)(wr2.y & 0xffff));
  float xr3 = bf2f((unsigned short)(wr2.y >> 16));
  uint2 wv0 = *(const uint2*)(xl + (size_t)wid * 128 + c0);
  float v0 = bf2f((unsigned short)(wv0.x & 0xffff));
  float v1 = bf2f((unsigned short)(wv0.x >> 16));
  float v2 = bf2f((unsigned short)(wv0.y & 0xffff));
  float v3 = bf2f((unsigned short)(wv0.y >> 16));
  float ep = lrelu(v0 + xr0) * at.x + lrelu(v1 + xr1) * at.y +
             lrelu(v2 + xr2) * at.z + lrelu(v3 + xr3) * at.w;
  #pragma unroll
  for (int off = 16; off > 0; off >>= 1) ep += __shfl_xor(ep, off, 64);
  float m = ep, s = 1.f, o0 = v0, o1 = v1, o2 = v2, o3 = v3;
  int beg = rowptr[wid], end = rowptr[wid + 1];
  for (int j0 = beg; j0 < end; j0 += 32) {
    int nv = end - j0; if (nv > 32) nv = 32;
    unsigned int pk = (l < nv) ? csr2[j0 + l] : 0u;
    for (int t = 0; t < nv; t += 8) {
      float u0[8], u1[8], u2[8], u3[8], p[8];
      #pragma unroll
      for (int z = 0; z < 8; z++) {
        unsigned int pv = (unsigned int)__shfl((int)pk, hb + t + z, 64);
        int src = (int)(pv & 0xFFFF);
        uint2 wu;
        if (t + z < nv) wu = *(const uint2*)(xl + (size_t)src * 128 + c0);
        else            wu = make_uint2(0, 0);
        u0[z] = bf2f((unsigned short)(wu.x & 0xffff));
        u1[z] = bf2f((unsigned short)(wu.x >> 16));
        u2[z] = bf2f((unsigned short)(wu.y & 0xffff));
        u3[z] = bf2f((unsigned short)(wu.y >> 16));
      }
      #pragma unroll
      for (int z = 0; z < 8; z++)
        p[z] = lrelu(u0[z] + xr0) * at.x + lrelu(u1[z] + xr1) * at.y +
               lrelu(u2[z] + xr2) * at.z + lrelu(u3[z] + xr3) * at.w;
      #pragma unroll
      for (int off = 16; off > 0; off >>= 1) {
        #pragma unroll
        for (int z = 0; z < 8; z++) p[z] += __shfl_xor(p[z], off, 64);
      }
      #pragma unroll
      for (int z = 0; z < 8; z++) if (t + z >= nv) p[z] = -1e30f;
      float pm = p[0];
      #pragma unroll
      for (int z = 1; z < 8; z++) pm = fmaxf(pm, p[z]);
      float mn = fmaxf(m, pm);
      float sc = __expf(m - mn);
      float e[8];
      #pragma unroll
      for (int z = 0; z < 8; z++) e[z] = __expf(p[z] - mn);
      float es = 0.f, e0 = 0.f, e1 = 0.f, e2 = 0.f, e3 = 0.f;
      #pragma unroll
      for (int z = 0; z < 8; z++) {
        es += e[z]; e0 += e[z] * u0[z]; e1 += e[z] * u1[z];
        e2 += e[z] * u2[z]; e3 += e[z] * u3[z];
      }
      s = s * sc + es;
      o0 = o0 * sc + e0; o1 = o1 * sc + e1;
      o2 = o2 * sc + e2; o3 = o3 * sc + e3;
      m = mn;
    }
  }
  float inv = 1.f / s;
  float4 b2 = *(const float4*)(bias2 + c0);
  float4 res = make_float4(o0 * inv + b2.x, o1 * inv + b2.y,
                           o2 * inv + b2.z, o3 * inv + b2.w);
  *(float4*)&out[(size_t)wid * H1 + c0] = res;
}

extern "C" void kernel_launch(void* const* d_in, const int* in_sizes, int n_in,
                              void* d_out, int out_size, void* d_ws, size_t ws_size,
                              hipStream_t stream) {
  const float* nf    = (const float*)d_in[0];
  const int*   ei    = (const int*)d_in[1];
  const int*   et    = (const int*)d_in[3];
  const float* basis = (const float*)d_in[4];
  const float* comp  = (const float*)d_in[5];
  const float* root  = (const float*)d_in[6];
  const float* bias1 = (const float*)d_in[7];
  const float* w_l   = (const float*)d_in[8];
  const float* w_r   = (const float*)d_in[9];
  const float* att   = (const float*)d_in[10];
  const float* bias2 = (const float*)d_in[11];
  float* out = (float*)d_out;

  char* ws = (char*)d_ws;
  unsigned short* xr_bf  = (unsigned short*)ws;                    // [NN][1024] 102.4 MB
  unsigned short* nf_bf  = (unsigned short*)(ws + 102400000);      // [NN][256]  25.6 MB
  unsigned short* wrb_t  = (unsigned short*)(ws + 128000000);      // [1024][256]
  unsigned short* btf    = (unsigned short*)(ws + 128524288);      // [256][384] bf16
  float*          biasv  = (float*)(ws + 128720896);               // [256]
  unsigned short* agg_bf = (unsigned short*)(ws + 128721920);      // [NN][128] bf16
  int*            cursor = (int*)(ws + 141521920);                 // [NN]
  int*            cnt2   = cursor + NN;                            // [NN*8]
  int*            rowptr = cnt2 + NN * NREL;                       // [NN+1]
  unsigned int*   csr    = (unsigned int*)(rowptr + NN + 1);       // [NE]
  int*            parts  = (int*)(csr + NE);                       // [64]
  // overlays into xr region (dead after k_rgcn): compact split outputs
  unsigned short* xl_bf  = (unsigned short*)ws;                    // [NN][128] 12.8 MB
  unsigned short* xrt_bf = (unsigned short*)(ws + 12800000);       // [NN][128] 12.8 MB

  hipMemsetAsync(cursor, 0, (1 + NREL) * NN * sizeof(int), stream);

  k_pre3<<<PRE_ALL_BLKS, 256, 0, stream>>>(nf, nf_bf, basis, comp, wrb_t,
                                           root, w_l, w_r, bias1, btf, biasv);

  const int GY128 = (NN + 127) / 128;   // 391
  k_mgemm<256, 4><<<8 * GY128, 256, 49152, stream>>>(
      nf_bf, wrb_t, xr_bf, NN, XRLD, 8);

  k_deg<<<(NE + 255) / 256, 256, 0, stream>>>(ei, et, cnt2);
  k_scan_a<<<NCHUNKS, 256, 0, stream>>>(cnt2, parts);
  k_scan_c<<<NCHUNKS, 256, 0, stream>>>(cnt2, parts, rowptr);
  k_scatter<<<(NE + 255) / 256, 256, 0, stream>>>(ei, et, rowptr, cnt2, cursor, csr);

  k_rgcn<<<(NN + 7) / 8, 256, 0, stream>>>(xr_bf, csr, rowptr, agg_bf);

  k_fused<<<2 * GY128, 256, 49152, stream>>>(agg_bf, nf_bf, btf, biasv, xl_bf, xrt_bf, NN);

  k_gat<<<(NN + 7) / 8, 256, 0, stream>>>(xl_bf, xrt_bf, csr, rowptr, att, bias2, out);
}